// Round 7
// baseline (186.923 us; speedup 1.0000x reference)
//
#include <hip/hip_runtime.h>
#include <math.h>

#define PI_F 3.14159265358979323846f
#define NB 8
#define NH 128
#define NL 4096
#define LF 2049    // NL/2 + 1
#define WB 2064    // padded per-batch column width (>=2049, mult of 16)
#define NT 16512   // WB * NB = total GEMM columns (= 129 * 128)

typedef float2 cpx;
typedef __attribute__((ext_vector_type(8))) short bf8v;   // 8 bf16 in 4 VGPRs
typedef __attribute__((ext_vector_type(4))) float f4;     // MFMA acc

#define MFMA16(a, b, c) __builtin_amdgcn_mfma_f32_16x16x32_bf16(a, b, c, 0, 0, 0)

__device__ __forceinline__ float gelu_exact(float x) {
  return 0.5f * x * (1.0f + erff(x * 0.70710678118654752f));
}
__device__ __forceinline__ unsigned short f2bf(float f) {
  unsigned int x = __float_as_uint(f);
  return (unsigned short)((x + 0x7FFFu + ((x >> 16) & 1u)) >> 16);
}
__device__ __forceinline__ float bf2f(unsigned short h) {
  return __uint_as_float((unsigned int)h << 16);
}
__device__ __forceinline__ unsigned int packpair(float re, float im) {
  return (unsigned int)f2bf(re) | ((unsigned int)f2bf(im) << 16);
}
__device__ __forceinline__ cpx cadd(cpx a, cpx b) { return make_float2(a.x + b.x, a.y + b.y); }
__device__ __forceinline__ cpx csub(cpx a, cpx b) { return make_float2(a.x - b.x, a.y - b.y); }
__device__ __forceinline__ cpx cmul(cpx a, cpx b) {
  return make_float2(fmaf(a.x, b.x, -a.y * b.y), fmaf(a.x, b.y, a.y * b.x));
}
template <int SGN>
__device__ __forceinline__ cpx mulJ(cpx a) {
  return (SGN < 0) ? make_float2(a.y, -a.x) : make_float2(-a.y, a.x);
}

// ---------------- precompute: C~ = F^-1 C, B~ = Bbar F, T = D F ----------------
__global__ __launch_bounds__(128) void precomp1(
    const float* __restrict__ C2, const float* __restrict__ B2,
    const float* __restrict__ D,
    float* __restrict__ Bt, float* __restrict__ Ct, float* __restrict__ Tt) {
  __shared__ float rc[128], rs[128];
  int x = blockIdx.x, t = threadIdx.x, which = blockIdx.y;
  { float s, c; sincosf(-(2.f * PI_F / 128.f) * (float)t, &s, &c); rc[t] = c; rs[t] = s; }
  __syncthreads();
  float sr = 0.f, si = 0.f;
  if (which == 0) {
    for (int k = 0; k < 128; ++k) {
      int j = (k * t) & 127; float c = rc[j], s = rs[j];
      float br = B2[(x * 128 + k) * 2], bi = B2[(x * 128 + k) * 2 + 1];
      sr += br * c - bi * s; si += br * s + bi * c;
    }
    Bt[(t * 128 + x) * 2] = sr; Bt[(t * 128 + x) * 2 + 1] = si;
  } else if (which == 1) {
    for (int k = 0; k < 128; ++k) {
      int j = (k * t) & 127; float c = rc[j], s = -rs[j];  // e^{+i theta}
      float cr = C2[(k * 128 + x) * 2], ci = C2[(k * 128 + x) * 2 + 1];
      sr += cr * c - ci * s; si += cr * s + ci * c;
    }
    Ct[(x * 128 + t) * 2] = sr * (1.f / 128.f);
    Ct[(x * 128 + t) * 2 + 1] = si * (1.f / 128.f);
  } else {
    for (int k = 0; k < 128; ++k) {
      int j = (k * t) & 127; float c = rc[j], s = rs[j];
      float d = D[x * 128 + k];
      sr += d * c; si += d * s;
    }
    Tt[(x * 128 + t) * 2] = sr; Tt[(x * 128 + t) * 2 + 1] = si;
  }
}

__global__ __launch_bounds__(128) void precomp2(const float* __restrict__ Tt,
                                                float* __restrict__ Dt) {
  __shared__ float rc[128], rs[128];
  int q = blockIdx.x, h = threadIdx.x;
  { float s, c; sincosf(-(2.f * PI_F / 128.f) * (float)h, &s, &c); rc[h] = c; rs[h] = s; }
  __syncthreads();
  float sr = 0.f, si = 0.f;
  for (int k = 0; k < 128; ++k) {
    int j = (k * h) & 127; float c = rc[j], s = -rs[j];    // e^{+i theta}
    float tr = Tt[(k * 128 + q) * 2], ti = Tt[(k * 128 + q) * 2 + 1];
    sr += tr * c - ti * s; si += tr * s + ti * c;
  }
  Dt[(q * 128 + h) * 2] = sr * (1.f / 128.f);
  Dt[(q * 128 + h) * 2 + 1] = si * (1.f / 128.f);
}

// ---------------- pack real GEMM matrices Mb (256x256), Mc (256x512), bf16 hi/lo ----------------
__global__ __launch_bounds__(256) void pack_mats(
    const float* __restrict__ Bt, const float* __restrict__ Ct, const float* __restrict__ Dt,
    unsigned short* __restrict__ Mbh, unsigned short* __restrict__ Mbl,
    unsigned short* __restrict__ Mch, unsigned short* __restrict__ Mcl) {
  int r = blockIdx.x, t = threadIdx.x;
  int p = r >> 1, par = r & 1;
  {
    int q = t >> 1, cq = t & 1;
    float br = Bt[(q * 128 + p) * 2], bi = Bt[(q * 128 + p) * 2 + 1];
    float v = par == 0 ? (cq == 0 ? br : -bi) : (cq == 0 ? bi : br);
    unsigned short h = f2bf(v);
    Mbh[r * 256 + t] = h; Mbl[r * 256 + t] = f2bf(v - bf2f(h));
  }
  for (int cc = 0; cc < 2; ++cc) {
    int c = t + cc * 256;
    float v;
    if (c < 256) {
      int pp = c >> 1, cq = c & 1;
      float cr = Ct[(pp * 128 + p) * 2], ci = Ct[(pp * 128 + p) * 2 + 1];
      v = par == 0 ? (cq == 0 ? cr : -ci) : (cq == 0 ? ci : cr);
    } else {
      int qq = (c - 256) >> 1, cq = c & 1;
      float dr = Dt[(qq * 128 + p) * 2], di = Dt[(qq * 128 + p) * 2 + 1];
      v = par == 0 ? (cq == 0 ? dr : -di) : (cq == 0 ? di : dr);
    }
    unsigned short h = f2bf(v);
    Mch[r * 512 + c] = h; Mcl[r * 512 + c] = f2bf(v - bf2f(h));
  }
}

// ---------------- register FFT-2048: radix 8*8*8*4, 256 threads ----------------
#define SW(k) ((k) ^ (((k) >> 4) & 31))

template <int SGN>
__device__ __forceinline__ void dft8(cpx a[8]) {
  cpx t0 = cadd(a[0], a[4]), u0 = csub(a[0], a[4]);
  cpx t1 = cadd(a[1], a[5]), u1 = csub(a[1], a[5]);
  cpx t2 = cadd(a[2], a[6]), u2 = csub(a[2], a[6]);
  cpx t3 = cadd(a[3], a[7]), u3 = csub(a[3], a[7]);
  cpx E0 = cadd(t0, t2), E2 = csub(t0, t2);
  cpx ju2 = mulJ<SGN>(u2);
  cpx E1 = cadd(u0, ju2), E3 = csub(u0, ju2);
  cpx O0 = cadd(t1, t3), O2 = csub(t1, t3);
  cpx ju3 = mulJ<SGN>(u3);
  cpx O1 = cadd(u1, ju3), O3 = csub(u1, ju3);
  const float r = 0.70710678118654752f;
  const float S = (float)SGN;
  cpx w1O1 = make_float2(r * (O1.x - S * O1.y), r * (O1.y + S * O1.x));
  cpx w3O3 = make_float2(r * (-O3.x - S * O3.y), r * (S * O3.x - O3.y));
  cpx jO2 = mulJ<SGN>(O2);
  a[0] = cadd(E0, O0);   a[4] = csub(E0, O0);
  a[1] = cadd(E1, w1O1); a[5] = csub(E1, w1O1);
  a[2] = cadd(E2, jO2);  a[6] = csub(E2, jO2);
  a[3] = cadd(E3, w3O3); a[7] = csub(E3, w3O3);
}

template <int SGN>
__device__ __forceinline__ void dft4(cpx b[4]) {
  cpx s0 = cadd(b[0], b[2]), d0 = csub(b[0], b[2]);
  cpx s1 = cadd(b[1], b[3]), d1 = csub(b[1], b[3]);
  cpx jd1 = mulJ<SGN>(d1);
  b[0] = cadd(s0, s1); b[2] = csub(s0, s1);
  b[1] = cadd(d0, jd1); b[3] = csub(d0, jd1);
}

__device__ __forceinline__ void twid8(cpx a[8], float ang) {
  float s, c; __sincosf(ang, &s, &c);
  cpx w1 = make_float2(c, s);
  cpx w2 = cmul(w1, w1), w3 = cmul(w2, w1), w4 = cmul(w2, w2);
  cpx w5 = cmul(w3, w2), w6 = cmul(w3, w3), w7 = cmul(w4, w3);
  a[1] = cmul(a[1], w1); a[2] = cmul(a[2], w2); a[3] = cmul(a[3], w3);
  a[4] = cmul(a[4], w4); a[5] = cmul(a[5], w5); a[6] = cmul(a[6], w6);
  a[7] = cmul(a[7], w7);
}

template <int SGN>
__device__ __forceinline__ void fft2048_core(cpx a[8], cpx* __restrict__ bufA,
                                             cpx* __restrict__ bufB, int t) {
  const float S = (float)SGN;
  dft8<SGN>(a);
  twid8(a, S * (2.f * PI_F / 2048.f) * (float)t);
#pragma unroll
  for (int p = 0; p < 8; ++p) bufA[p * 264 + t] = a[p];
  __syncthreads();
  int p = t >> 5, n1 = t & 31;
#pragma unroll
  for (int j = 0; j < 8; ++j) a[j] = bufA[p * 264 + n1 + 32 * j];
  dft8<SGN>(a);
  twid8(a, S * (2.f * PI_F / 256.f) * (float)n1);
#pragma unroll
  for (int q = 0; q < 8; ++q) bufB[p * 264 + q * 33 + n1] = a[q];
  __syncthreads();
  int q = (t >> 2) & 7, n2 = t & 3;
#pragma unroll
  for (int j = 0; j < 8; ++j) a[j] = bufB[p * 264 + q * 33 + n2 + 4 * j];
  dft8<SGN>(a);
  twid8(a, S * (2.f * PI_F / 32.f) * (float)n2);
#pragma unroll
  for (int d = 0; d < 8; ++d) bufA[p * 264 + q * 33 + 4 * d + n2] = a[d];
  __syncthreads();
#pragma unroll
  for (int h = 0; h < 2; ++h) {
    int d = 2 * n2 + h;
    cpx b[4];
#pragma unroll
    for (int m = 0; m < 4; ++m) b[m] = bufA[p * 264 + q * 33 + 4 * d + m];
    dft4<SGN>(b);
    int kb = p + 8 * q + 64 * d;
#pragma unroll
    for (int c = 0; c < 4; ++c) bufB[SW(kb + 512 * c)] = b[c];
  }
  __syncthreads();
}

// ---------------- forward rfft-4096 -> bf16 hi/lo pair planes U[q][col] ----------------
// Plane layout: Uph[q*NT + col] = dword (bf16 re | bf16 im << 16). Fully coalesced stores.
__global__ __launch_bounds__(256) void fft_fwd_pack(const float* __restrict__ u,
                                                    unsigned int* __restrict__ Uph,
                                                    unsigned int* __restrict__ Upl) {
  __shared__ cpx bufA[2112], bufB[2112];
  int t = threadIdx.x;
  int row = blockIdx.x;
  int b = row >> 7, q = row & 127;
  const cpx* src = (const cpx*)(u + (size_t)row * NL);
  cpx a[8];
#pragma unroll
  for (int j = 0; j < 8; ++j) a[j] = src[t + 256 * j];
  fft2048_core<-1>(a, bufA, bufB, t);
  unsigned int* Uh = Uph + (size_t)q * NT + (size_t)b * WB;
  unsigned int* Ul = Upl + (size_t)q * NT + (size_t)b * WB;
  auto pstore = [&](int k, float ur, float ui) {
    Uh[k] = packpair(ur, ui);
    Ul[k] = packpair(ur - bf2f(f2bf(ur)), ui - bf2f(f2bf(ui)));
  };
#pragma unroll
  for (int r = 0; r < 4; ++r) {
    int k = t + (r << 8);
    if (k == 0) {
      cpx z0 = bufB[SW(0)];
      pstore(0, z0.x + z0.y, 0.f);
      pstore(2048, z0.x - z0.y, 0.f);
      cpx zN = bufB[SW(1024)];
      pstore(1024, zN.x, -zN.y);
    } else {
      cpx A = bufB[SW(k)];
      cpx M = bufB[SW(2048 - k)];
      float Br = M.x, Bi = -M.y;
      float sr = 0.5f * (A.x + Br), si = 0.5f * (A.y + Bi);
      float dr = 0.5f * (A.x - Br), di = 0.5f * (A.y - Bi);
      float th = (float)k * (PI_F / 2048.f);
      float sn, cs; __sincosf(th, &sn, &cs);
      float tr = cs * dr + sn * di;
      float ti = cs * di - sn * dr;
      pstore(k, sr + ti, si - tr);
      float A2r = M.x, A2i = M.y;
      float B2r = A.x, B2i = -A.y;
      float s2r = 0.5f * (A2r + B2r), s2i = 0.5f * (A2i + B2i);
      float d2r = 0.5f * (A2r - B2r), d2i = 0.5f * (A2i - B2i);
      float t2r = -cs * d2r + sn * d2i;
      float t2i = -cs * d2i - sn * d2r;
      pstore(2048 - k, s2r + t2i, s2i - t2r);
    }
  }
}

// ---------------- GEMM B-panel staging from pair planes into frag-layout LDS ----------------
// LDS: [quad 0..3][col 0..127][8 ushorts]; frag = 8 consecutive ushorts (b128 read).
__device__ __forceinline__ void stageB(const unsigned int* __restrict__ Sh,
                                       const unsigned int* __restrict__ Sl,
                                       int qt, int j0, int tid,
                                       unsigned short* __restrict__ Bh,
                                       unsigned short* __restrict__ Bl) {
  int col = tid & 127, grp = tid >> 7;
#pragma unroll
  for (int gg = 0; gg < 2; ++gg) {
    int g = grp + 2 * gg;
    uint4 hv, lv;
    size_t base = (size_t)(qt + g * 4) * NT + j0 + col;
    hv.x = Sh[base];           lv.x = Sl[base];
    hv.y = Sh[base + NT];      lv.y = Sl[base + NT];
    hv.z = Sh[base + 2 * NT];  lv.z = Sl[base + 2 * NT];
    hv.w = Sh[base + 3 * NT];  lv.w = Sl[base + 3 * NT];
    *(uint4*)&Bh[(g * 128 + col) * 8] = hv;
    *(uint4*)&Bl[(g * 128 + col) * 8] = lv;
  }
}

// ---------------- GEMM1: V2 = Mb x U2 (split-bf16, 3 MFMA), scale, pair-plane store ----------------
// Block: M=128 x N=128; waves 2x2; acc[4][4]; BK=32; grid (2, 129).
__global__ __launch_bounds__(256, 2) void gemm1(
    const unsigned short* __restrict__ Mbh, const unsigned short* __restrict__ Mbl,
    const unsigned int* __restrict__ Uph, const unsigned int* __restrict__ Upl,
    const float* __restrict__ Lam,
    unsigned int* __restrict__ Vph, unsigned int* __restrict__ Vpl) {
  __shared__ unsigned short Ah[4096], Al[4096], Bh[4096], Bl[4096];
  int tid = threadIdx.x;
  int i0 = blockIdx.x * 128;
  int j0 = blockIdx.y * 128;
  int w = tid >> 6, lane = tid & 63, quad = lane >> 4, ln = lane & 15;
  int mw = w & 1, nw = w >> 1;
  f4 acc[4][4];
#pragma unroll
  for (int mt = 0; mt < 4; ++mt)
#pragma unroll
    for (int nt = 0; nt < 4; ++nt) acc[mt][nt] = (f4){0.f, 0.f, 0.f, 0.f};

  for (int kt = 0; kt < 256; kt += 32) {
    __syncthreads();
#pragma unroll
    for (int r = 0; r < 2; ++r) {
      int j = tid + 256 * r; int m = j >> 2, cch = j & 3;
      int slot = (m * 4 + (cch ^ (m & 3))) * 8;   // XOR swizzle vs bank conflicts
      size_t go = (size_t)(i0 + m) * 256 + kt + cch * 8;
      *(uint4*)&Ah[slot] = *(const uint4*)&Mbh[go];
      *(uint4*)&Al[slot] = *(const uint4*)&Mbl[go];
    }
    stageB(Uph, Upl, kt >> 1, j0, tid, Bh, Bl);
    __syncthreads();
    bf8v ah[4], al[4], bh[4], bl[4];
#pragma unroll
    for (int mt = 0; mt < 4; ++mt) {
      int m = mw * 64 + mt * 16 + ln;
      int off = (m * 4 + (quad ^ (m & 3))) * 8;
      ah[mt] = *(const bf8v*)&Ah[off];
      al[mt] = *(const bf8v*)&Al[off];
    }
#pragma unroll
    for (int nt = 0; nt < 4; ++nt) {
      int off = (quad * 128 + nw * 64 + nt * 16 + ln) * 8;
      bh[nt] = *(const bf8v*)&Bh[off];
      bl[nt] = *(const bf8v*)&Bl[off];
    }
#pragma unroll
    for (int mt = 0; mt < 4; ++mt)
#pragma unroll
      for (int nt = 0; nt < 4; ++nt) {
        acc[mt][nt] = MFMA16(ah[mt], bh[nt], acc[mt][nt]);
        acc[mt][nt] = MFMA16(ah[mt], bl[nt], acc[mt][nt]);
        acc[mt][nt] = MFMA16(al[mt], bh[nt], acc[mt][nt]);
      }
  }
  // epilogue: Cauchy-kernel scale; coalesced pair-plane stores
#pragma unroll
  for (int mt = 0; mt < 4; ++mt) {
    int r0 = i0 + mw * 64 + mt * 16 + quad * 4;   // multiple of 4
    int p0 = r0 >> 1;                              // even
    float2 lam0 = ((const float2*)Lam)[p0];
    float2 lam1 = ((const float2*)Lam)[p0 + 1];
#pragma unroll
    for (int nt = 0; nt < 4; ++nt) {
      int col = j0 + nw * 64 + nt * 16 + ln;
      int bb = col / WB; int l = col - bb * WB;
      float omega = (float)l * (PI_F / 2048.f);
      f4 a = acc[mt][nt];
      float dx0 = -lam0.x, dy0 = omega - lam0.y;
      float inv0 = 1.f / (dx0 * dx0 + dy0 * dy0);
      float kr0 = dx0 * inv0, ki0 = -dy0 * inv0;
      float v0r = kr0 * a[0] - ki0 * a[1];
      float v0i = kr0 * a[1] + ki0 * a[0];
      float dx1 = -lam1.x, dy1 = omega - lam1.y;
      float inv1 = 1.f / (dx1 * dx1 + dy1 * dy1);
      float kr1 = dx1 * inv1, ki1 = -dy1 * inv1;
      float v1r = kr1 * a[2] - ki1 * a[3];
      float v1i = kr1 * a[3] + ki1 * a[2];
      size_t i0v = (size_t)p0 * NT + col;
      size_t i1v = (size_t)(p0 + 1) * NT + col;
      Vph[i0v] = packpair(v0r, v0i);
      Vpl[i0v] = packpair(v0r - bf2f(f2bf(v0r)), v0i - bf2f(f2bf(v0i)));
      Vph[i1v] = packpair(v1r, v1i);
      Vpl[i1v] = packpair(v1r - bf2f(f2bf(v1r)), v1i - bf2f(f2bf(v1i)));
    }
  }
}

// ---------------- GEMM2: Y2 = Mc x [V2'; U2], float2 pair output Y[h][col] ----------------
__global__ __launch_bounds__(256, 2) void gemm2(
    const unsigned short* __restrict__ Mch, const unsigned short* __restrict__ Mcl,
    const unsigned int* __restrict__ Vph, const unsigned int* __restrict__ Vpl,
    const unsigned int* __restrict__ Uph, const unsigned int* __restrict__ Upl,
    float2* __restrict__ Yp) {
  __shared__ unsigned short Ah[4096], Al[4096], Bh[4096], Bl[4096];
  int tid = threadIdx.x;
  int i0 = blockIdx.x * 128;
  int j0 = blockIdx.y * 128;
  int w = tid >> 6, lane = tid & 63, quad = lane >> 4, ln = lane & 15;
  int mw = w & 1, nw = w >> 1;
  f4 acc[4][4];
#pragma unroll
  for (int mt = 0; mt < 4; ++mt)
#pragma unroll
    for (int nt = 0; nt < 4; ++nt) acc[mt][nt] = (f4){0.f, 0.f, 0.f, 0.f};

  for (int kt = 0; kt < 512; kt += 32) {
    __syncthreads();
#pragma unroll
    for (int r = 0; r < 2; ++r) {
      int j = tid + 256 * r; int m = j >> 2, cch = j & 3;
      int slot = (m * 4 + (cch ^ (m & 3))) * 8;
      size_t go = (size_t)(i0 + m) * 512 + kt + cch * 8;
      *(uint4*)&Ah[slot] = *(const uint4*)&Mch[go];
      *(uint4*)&Al[slot] = *(const uint4*)&Mcl[go];
    }
    if (kt < 256) stageB(Vph, Vpl, kt >> 1, j0, tid, Bh, Bl);
    else          stageB(Uph, Upl, (kt - 256) >> 1, j0, tid, Bh, Bl);
    __syncthreads();
    bf8v ah[4], al[4], bh[4], bl[4];
#pragma unroll
    for (int mt = 0; mt < 4; ++mt) {
      int m = mw * 64 + mt * 16 + ln;
      int off = (m * 4 + (quad ^ (m & 3))) * 8;
      ah[mt] = *(const bf8v*)&Ah[off];
      al[mt] = *(const bf8v*)&Al[off];
    }
#pragma unroll
    for (int nt = 0; nt < 4; ++nt) {
      int off = (quad * 128 + nw * 64 + nt * 16 + ln) * 8;
      bh[nt] = *(const bf8v*)&Bh[off];
      bl[nt] = *(const bf8v*)&Bl[off];
    }
#pragma unroll
    for (int mt = 0; mt < 4; ++mt)
#pragma unroll
      for (int nt = 0; nt < 4; ++nt) {
        acc[mt][nt] = MFMA16(ah[mt], bh[nt], acc[mt][nt]);
        acc[mt][nt] = MFMA16(ah[mt], bl[nt], acc[mt][nt]);
        acc[mt][nt] = MFMA16(al[mt], bh[nt], acc[mt][nt]);
      }
  }
#pragma unroll
  for (int mt = 0; mt < 4; ++mt) {
    int r0 = i0 + mw * 64 + mt * 16 + quad * 4;
    int h0 = r0 >> 1;   // even
#pragma unroll
    for (int nt = 0; nt < 4; ++nt) {
      int col = j0 + nw * 64 + nt * 16 + ln;
      f4 a = acc[mt][nt];
      Yp[(size_t)h0 * NT + col] = make_float2(a[0], a[1]);
      Yp[(size_t)(h0 + 1) * NT + col] = make_float2(a[2], a[3]);
    }
  }
}

// ---------------- inverse rfft-4096 from float2 pair planes, fused exact GELU ----------------
__global__ __launch_bounds__(256) void fft_inv_gelu_pl(const float2* __restrict__ Yp,
                                                       float* __restrict__ out) {
  __shared__ cpx bufA[2112], bufB[2112];
  int t = threadIdx.x;
  int row = blockIdx.x;
  int b = row >> 7, h = row & 127;
  const float2* Yrow = Yp + (size_t)h * NT + (size_t)b * WB;
#pragma unroll
  for (int r = 0; r < 4; ++r) {
    int k = t + (r << 8);
    if (k == 0) {
      float y0 = Yrow[0].x;     // Im discarded (pocketfft irfft semantics)
      float yN = Yrow[2048].x;
      bufB[SW(0)] = make_float2(0.5f * (y0 + yN), 0.5f * (y0 - yN));
      float2 z = Yrow[1024];
      bufB[SW(1024)] = make_float2(z.x, -z.y);
    } else {
      float2 A = Yrow[k];
      float2 M = Yrow[2048 - k];
      float Br = M.x, Bi = -M.y;
      float sr = 0.5f * (A.x + Br), si = 0.5f * (A.y + Bi);
      float dr = 0.5f * (A.x - Br), di = 0.5f * (A.y - Bi);
      float th = (float)k * (PI_F / 2048.f);
      float sn, cs; __sincosf(th, &sn, &cs);
      float e1 = cs * di + sn * dr;
      float e2 = cs * dr - sn * di;
      bufB[SW(k)] = make_float2(sr - e1, si + e2);
      bufB[SW(2048 - k)] = make_float2(sr + e1, -si + e2);
    }
  }
  __syncthreads();
  cpx a[8];
#pragma unroll
  for (int j = 0; j < 8; ++j) a[j] = bufB[SW(t + 256 * j)];
  fft2048_core<1>(a, bufA, bufB, t);
  float2* dst = (float2*)(out + (size_t)row * NL);
  const float sc = 1.f / 2048.f;
#pragma unroll
  for (int r = 0; r < 8; ++r) {
    int n = t + (r << 8);
    cpx z = bufB[SW(n)];
    dst[n] = make_float2(gelu_exact(z.x * sc), gelu_exact(z.y * sc));
  }
}

// ================= FALLBACK (used only if ws too small) =================
__global__ __launch_bounds__(256) void fb_fft_fwd(const float* __restrict__ u,
                                                  cpx* __restrict__ U) {
  __shared__ cpx bufA[2112], bufB[2112];
  int t = threadIdx.x;
  int row = blockIdx.x;
  const cpx* src = (const cpx*)(u + (size_t)row * NL);
  cpx a[8];
#pragma unroll
  for (int j = 0; j < 8; ++j) a[j] = src[t + 256 * j];
  fft2048_core<-1>(a, bufA, bufB, t);
  cpx* Urow = U + (size_t)row * LF;
#pragma unroll
  for (int r = 0; r < 4; ++r) {
    int k = t + (r << 8);
    if (k == 0) {
      cpx z0 = bufB[SW(0)];
      Urow[0] = make_float2(z0.x + z0.y, 0.f);
      Urow[2048] = make_float2(z0.x - z0.y, 0.f);
      cpx zN = bufB[SW(1024)];
      Urow[1024] = make_float2(zN.x, -zN.y);
    } else {
      cpx A = bufB[SW(k)];
      cpx M = bufB[SW(2048 - k)];
      float Br = M.x, Bi = -M.y;
      float sr = 0.5f * (A.x + Br), si = 0.5f * (A.y + Bi);
      float dr = 0.5f * (A.x - Br), di = 0.5f * (A.y - Bi);
      float th = (float)k * (PI_F / 2048.f);
      float sn, cs; __sincosf(th, &sn, &cs);
      float tr = cs * dr + sn * di;
      float ti = cs * di - sn * dr;
      Urow[k] = make_float2(sr + ti, si - tr);
      float A2r = M.x, A2i = M.y;
      float B2r = A.x, B2i = -A.y;
      float s2r = 0.5f * (A2r + B2r), s2i = 0.5f * (A2i + B2i);
      float d2r = 0.5f * (A2r - B2r), d2i = 0.5f * (A2i - B2i);
      float t2r = -cs * d2r + sn * d2i;
      float t2i = -cs * d2i - sn * d2r;
      Urow[2048 - k] = make_float2(s2r + t2i, s2i - t2r);
    }
  }
}

__device__ __forceinline__ void ld4(float4 d[4], const float4* __restrict__ p) {
#pragma unroll
  for (int kk = 0; kk < 4; ++kk) d[kk] = p[kk];
}
__device__ __forceinline__ void cmac4(const float4 m[4], float xr, float xi,
                                      float ar[8], float ai[8]) {
#pragma unroll
  for (int kk = 0; kk < 4; ++kk) {
    float4 v = m[kk];
    ar[2 * kk]     = fmaf(v.x, xr, fmaf(-v.y, xi, ar[2 * kk]));
    ai[2 * kk]     = fmaf(v.x, xi, fmaf( v.y, xr, ai[2 * kk]));
    ar[2 * kk + 1] = fmaf(v.z, xr, fmaf(-v.w, xi, ar[2 * kk + 1]));
    ai[2 * kk + 1] = fmaf(v.z, xi, fmaf( v.w, xr, ai[2 * kk + 1]));
  }
}

__global__ __launch_bounds__(256) void fb_mix(
    const cpx* __restrict__ U,
    const float* __restrict__ Bt, const float* __restrict__ Ct,
    const float* __restrict__ Dt, const float* __restrict__ Lam,
    cpx* __restrict__ Y) {
  __shared__ cpx sU[128][17], sV[128][17];
  int tid = threadIdx.x;
  int b = blockIdx.y;
  size_t ub = (size_t)b * NH * LF;
  if (blockIdx.x == 128) {
    int t = tid;
    if (t < 128) sU[t][0] = U[ub + (size_t)t * LF + 2048];
    __syncthreads();
    if (t < 128) {
      float ar = 0.f, ai = 0.f;
      for (int q = 0; q < 128; ++q) {
        float ur = sU[q][0].x, ui = sU[q][0].y;
        float br = Bt[(q * 128 + t) * 2], bi = Bt[(q * 128 + t) * 2 + 1];
        ar = fmaf(br, ur, fmaf(-bi, ui, ar));
        ai = fmaf(br, ui, fmaf(bi, ur, ai));
      }
      float a = Lam[2 * t], bb = Lam[2 * t + 1];
      float dx = -a, dy = PI_F - bb;
      float inv = 1.f / (dx * dx + dy * dy);
      float kr = dx * inv, ki = -dy * inv;
      sV[t][0] = make_float2(kr * ar - ki * ai, kr * ai + ki * ar);
    }
    __syncthreads();
    if (t < 128) {
      float ar = 0.f, ai = 0.f;
      for (int q = 0; q < 128; ++q) {
        float ur = sU[q][0].x, ui = sU[q][0].y;
        float vr = sV[q][0].x, vi = sV[q][0].y;
        float cr = Ct[(q * 128 + t) * 2], ci = Ct[(q * 128 + t) * 2 + 1];
        float dr = Dt[(q * 128 + t) * 2], di = Dt[(q * 128 + t) * 2 + 1];
        ar += cr * vr - ci * vi + dr * ur - di * ui;
        ai += cr * vi + ci * vr + dr * ui + di * ur;
      }
      Y[ub + (size_t)t * LF + 2048] = make_float2(ar, ai);
    }
    return;
  }
  int lane = tid & 15, g = tid >> 4;
  int l = blockIdx.x * 16 + lane;
#pragma unroll
  for (int rep = 0; rep < 8; ++rep) {
    int q = rep * 16 + g;
    sU[q][lane] = U[ub + (size_t)q * LF + l];
  }
  __syncthreads();
  float omega = (float)l * (PI_F / 2048.f);
  float ar[8], ai[8];
  {
#pragma unroll
    for (int k = 0; k < 8; ++k) { ar[k] = 0.f; ai[k] = 0.f; }
    const float4* base = (const float4*)Bt + g * 4;
    float4 e[4], o[4];
    ld4(e, base);
#pragma unroll 1
    for (int q = 0; q < 128; q += 2) {
      ld4(o, base + (q + 1) * 64);
      cpx u0 = sU[q][lane];
      cmac4(e, u0.x, u0.y, ar, ai);
      ld4(e, base + ((q + 2) & 127) * 64);
      cpx u1 = sU[q + 1][lane];
      cmac4(o, u1.x, u1.y, ar, ai);
    }
    int p0 = g * 8;
#pragma unroll
    for (int k = 0; k < 8; ++k) {
      int p = p0 + k;
      float a = Lam[2 * p], bb = Lam[2 * p + 1];
      float dx = -a, dy = omega - bb;
      float inv = 1.f / (dx * dx + dy * dy);
      float kr = dx * inv, ki = -dy * inv;
      sV[p][lane] = make_float2(kr * ar[k] - ki * ai[k], kr * ai[k] + ki * ar[k]);
    }
  }
  __syncthreads();
  {
#pragma unroll
    for (int k = 0; k < 8; ++k) { ar[k] = 0.f; ai[k] = 0.f; }
    const float4* base = (const float4*)Ct + g * 4;
    float4 e[4], o[4];
    ld4(e, base);
#pragma unroll 1
    for (int q = 0; q < 128; q += 2) {
      ld4(o, base + (q + 1) * 64);
      cpx v0 = sV[q][lane];
      cmac4(e, v0.x, v0.y, ar, ai);
      ld4(e, base + ((q + 2) & 127) * 64);
      cpx v1 = sV[q + 1][lane];
      cmac4(o, v1.x, v1.y, ar, ai);
    }
  }
  {
    const float4* base = (const float4*)Dt + g * 4;
    float4 e[4], o[4];
    ld4(e, base);
#pragma unroll 1
    for (int q = 0; q < 128; q += 2) {
      ld4(o, base + (q + 1) * 64);
      cpx u0 = sU[q][lane];
      cmac4(e, u0.x, u0.y, ar, ai);
      ld4(e, base + ((q + 2) & 127) * 64);
      cpx u1 = sU[q + 1][lane];
      cmac4(o, u1.x, u1.y, ar, ai);
    }
  }
  int h0 = g * 8;
#pragma unroll
  for (int k = 0; k < 8; ++k) {
    Y[ub + (size_t)(h0 + k) * LF + l] = make_float2(ar[k], ai[k]);
  }
}

__global__ __launch_bounds__(256) void fb_fft_inv(const cpx* __restrict__ Y,
                                                  float* __restrict__ out) {
  __shared__ cpx bufA[2112], bufB[2112];
  int t = threadIdx.x;
  int row = blockIdx.x;
  const cpx* Yrow = Y + (size_t)row * LF;
#pragma unroll
  for (int r = 0; r < 4; ++r) {
    int k = t + (r << 8);
    if (k == 0) {
      float y0 = Yrow[0].x;
      float yN = Yrow[2048].x;
      bufB[SW(0)] = make_float2(0.5f * (y0 + yN), 0.5f * (y0 - yN));
      cpx z = Yrow[1024];
      bufB[SW(1024)] = make_float2(z.x, -z.y);
    } else {
      cpx A = Yrow[k];
      cpx M = Yrow[2048 - k];
      float Br = M.x, Bi = -M.y;
      float sr = 0.5f * (A.x + Br), si = 0.5f * (A.y + Bi);
      float dr = 0.5f * (A.x - Br), di = 0.5f * (A.y - Bi);
      float th = (float)k * (PI_F / 2048.f);
      float sn, cs; __sincosf(th, &sn, &cs);
      float e1 = cs * di + sn * dr;
      float e2 = cs * dr - sn * di;
      bufB[SW(k)] = make_float2(sr - e1, si + e2);
      bufB[SW(2048 - k)] = make_float2(sr + e1, -si + e2);
    }
  }
  __syncthreads();
  cpx a[8];
#pragma unroll
  for (int j = 0; j < 8; ++j) a[j] = bufB[SW(t + 256 * j)];
  fft2048_core<1>(a, bufA, bufB, t);
  float2* dst = (float2*)(out + (size_t)row * NL);
  const float sc = 1.f / 2048.f;
#pragma unroll
  for (int r = 0; r < 8; ++r) {
    int n = t + (r << 8);
    cpx z = bufB[SW(n)];
    dst[n] = make_float2(gelu_exact(z.x * sc), gelu_exact(z.y * sc));
  }
}

extern "C" void kernel_launch(void* const* d_in, const int* in_sizes, int n_in,
                              void* d_out, int out_size, void* d_ws, size_t ws_size,
                              hipStream_t stream) {
  const float* u   = (const float*)d_in[0];
  const float* C2  = (const float*)d_in[1];
  const float* B2  = (const float*)d_in[2];
  const float* D   = (const float*)d_in[3];
  const float* Lam = (const float*)d_in[4];
  float* out = (float*)d_out;

  const size_t PL = (size_t)128 * NT;                 // dwords per pair plane
  const size_t need = PL * 4 * 4                      // Uph/Upl/Vph/Vpl (dword each)
                    + PL * 8                          // Yp float2
                    + 4 * 32768 * 4                   // Bt, Ct, Dt, Tt fp32
                    + 2 * 65536 * 2 + 2 * 131072 * 2; // Mb, Mc bf16 hi/lo

  if (ws_size >= need) {
    unsigned int* Uph = (unsigned int*)d_ws;
    unsigned int* Upl = Uph + PL;
    unsigned int* Vph = Upl + PL;
    unsigned int* Vpl = Vph + PL;
    float2* Yp = (float2*)(Vpl + PL);
    float* Bt = (float*)(Yp + PL);
    float* Ct = Bt + 32768;
    float* Dt = Ct + 32768;
    float* Tt = Dt + 32768;
    unsigned short* Mbh = (unsigned short*)(Tt + 32768);
    unsigned short* Mbl = Mbh + 65536;
    unsigned short* Mch = Mbl + 65536;
    unsigned short* Mcl = Mch + 131072;

    precomp1<<<dim3(128, 3), 128, 0, stream>>>(C2, B2, D, Bt, Ct, Tt);
    precomp2<<<128, 128, 0, stream>>>(Tt, Dt);
    pack_mats<<<256, 256, 0, stream>>>(Bt, Ct, Dt, Mbh, Mbl, Mch, Mcl);
    fft_fwd_pack<<<NB * NH, 256, 0, stream>>>(u, Uph, Upl);
    gemm1<<<dim3(2, NT / 128), 256, 0, stream>>>(Mbh, Mbl, Uph, Upl, Lam, Vph, Vpl);
    gemm2<<<dim3(2, NT / 128), 256, 0, stream>>>(Mch, Mcl, Vph, Vpl, Uph, Upl, Yp);
    fft_inv_gelu_pl<<<NB * NH, 256, 0, stream>>>(Yp, out);
  } else {
    float* ws = (float*)d_ws;
    const size_t nUc = (size_t)NB * NH * LF;
    cpx* U  = (cpx*)ws;
    cpx* Yf = U;
    float* Bt = ws + 2 * nUc;
    float* Ct = Bt + 32768;
    float* Dt = Ct + 32768;
    float* Tt = Dt + 32768;
    precomp1<<<dim3(128, 3), 128, 0, stream>>>(C2, B2, D, Bt, Ct, Tt);
    precomp2<<<128, 128, 0, stream>>>(Tt, Dt);
    fb_fft_fwd<<<NB * NH, 256, 0, stream>>>(u, U);
    fb_mix<<<dim3(129, NB), 256, 0, stream>>>(U, Bt, Ct, Dt, Lam, Yf);
    fb_fft_inv<<<NB * NH, 256, 0, stream>>>(Yf, out);
  }
}

// Round 8
// 156.032 us; speedup vs baseline: 1.1980x; 1.1980x over previous
//
#include <hip/hip_runtime.h>
#include <math.h>

#define PI_F 3.14159265358979323846f
#define NB 8
#define NH 128
#define NL 4096
#define LF 2049    // NL/2 + 1
#define WB 2064    // padded per-batch column width (>=2049, mult of 16)
#define NT 16512   // WB * NB = total GEMM columns (= 129 * 128)

typedef float2 cpx;
typedef __attribute__((ext_vector_type(8))) short bf8v;   // 8 bf16 in 4 VGPRs
typedef __attribute__((ext_vector_type(4))) float f4;     // MFMA acc

#define MFMA16(a, b, c) __builtin_amdgcn_mfma_f32_16x16x32_bf16(a, b, c, 0, 0, 0)

__device__ __forceinline__ float gelu_exact(float x) {
  return 0.5f * x * (1.0f + erff(x * 0.70710678118654752f));
}
__device__ __forceinline__ unsigned short f2bf(float f) {
  unsigned int x = __float_as_uint(f);
  return (unsigned short)((x + 0x7FFFu + ((x >> 16) & 1u)) >> 16);
}
__device__ __forceinline__ float bf2f(unsigned short h) {
  return __uint_as_float((unsigned int)h << 16);
}
__device__ __forceinline__ unsigned int packpair(float re, float im) {
  return (unsigned int)f2bf(re) | ((unsigned int)f2bf(im) << 16);
}
__device__ __forceinline__ cpx cadd(cpx a, cpx b) { return make_float2(a.x + b.x, a.y + b.y); }
__device__ __forceinline__ cpx csub(cpx a, cpx b) { return make_float2(a.x - b.x, a.y - b.y); }
__device__ __forceinline__ cpx cmul(cpx a, cpx b) {
  return make_float2(fmaf(a.x, b.x, -a.y * b.y), fmaf(a.x, b.y, a.y * b.x));
}
template <int SGN>
__device__ __forceinline__ cpx mulJ(cpx a) {
  return (SGN < 0) ? make_float2(a.y, -a.x) : make_float2(-a.y, a.x);
}

// ---------------- precompute: C~ = F^-1 C, B~ = Bbar F, D~ = F^-1 D F ----------------
// which==2 now computes D~ end-to-end (T column staged in LDS) — precomp2 folded in.
__global__ __launch_bounds__(128) void precomp1(
    const float* __restrict__ C2, const float* __restrict__ B2,
    const float* __restrict__ D,
    float* __restrict__ Bt, float* __restrict__ Ct, float* __restrict__ Dt) {
  __shared__ float rc[128], rs[128];
  __shared__ float sTr[128], sTi[128];
  int x = blockIdx.x, t = threadIdx.x, which = blockIdx.y;
  { float s, c; sincosf(-(2.f * PI_F / 128.f) * (float)t, &s, &c); rc[t] = c; rs[t] = s; }
  __syncthreads();
  float sr = 0.f, si = 0.f;
  if (which == 0) {
    for (int k = 0; k < 128; ++k) {
      int j = (k * t) & 127; float c = rc[j], s = rs[j];
      float br = B2[(x * 128 + k) * 2], bi = B2[(x * 128 + k) * 2 + 1];
      sr += br * c - bi * s; si += br * s + bi * c;
    }
    Bt[(t * 128 + x) * 2] = sr; Bt[(t * 128 + x) * 2 + 1] = si;
  } else if (which == 1) {
    for (int k = 0; k < 128; ++k) {
      int j = (k * t) & 127; float c = rc[j], s = -rs[j];  // e^{+i theta}
      float cr = C2[(k * 128 + x) * 2], ci = C2[(k * 128 + x) * 2 + 1];
      sr += cr * c - ci * s; si += cr * s + ci * c;
    }
    Ct[(x * 128 + t) * 2] = sr * (1.f / 128.f);
    Ct[(x * 128 + t) * 2 + 1] = si * (1.f / 128.f);
  } else {
    // phase 1: T[t][x] = sum_{q'} D[t][q'] e^{-2pi i q' x/128}
    for (int k = 0; k < 128; ++k) {
      int j = (k * x) & 127; float c = rc[j], s = rs[j];
      float d = D[t * 128 + k];
      sr += d * c; si += d * s;
    }
    sTr[t] = sr; sTi[t] = si;
    __syncthreads();
    // phase 2: D~[h=t][x] = (1/128) sum_k e^{+2pi i k t/128} T[k][x]
    sr = 0.f; si = 0.f;
    for (int k = 0; k < 128; ++k) {
      int j = (k * t) & 127; float c = rc[j], s = -rs[j];
      sr += sTr[k] * c - sTi[k] * s;
      si += sTr[k] * s + sTi[k] * c;
    }
    Dt[(x * 128 + t) * 2] = sr * (1.f / 128.f);
    Dt[(x * 128 + t) * 2 + 1] = si * (1.f / 128.f);
  }
}

// ---------------- pack real GEMM matrices Mb (256x256), Mc (256x512), bf16 hi/lo ----------------
__global__ __launch_bounds__(256) void pack_mats(
    const float* __restrict__ Bt, const float* __restrict__ Ct, const float* __restrict__ Dt,
    unsigned short* __restrict__ Mbh, unsigned short* __restrict__ Mbl,
    unsigned short* __restrict__ Mch, unsigned short* __restrict__ Mcl) {
  int r = blockIdx.x, t = threadIdx.x;
  int p = r >> 1, par = r & 1;
  {
    int q = t >> 1, cq = t & 1;
    float br = Bt[(q * 128 + p) * 2], bi = Bt[(q * 128 + p) * 2 + 1];
    float v = par == 0 ? (cq == 0 ? br : -bi) : (cq == 0 ? bi : br);
    unsigned short h = f2bf(v);
    Mbh[r * 256 + t] = h; Mbl[r * 256 + t] = f2bf(v - bf2f(h));
  }
  for (int cc = 0; cc < 2; ++cc) {
    int c = t + cc * 256;
    float v;
    if (c < 256) {
      int pp = c >> 1, cq = c & 1;
      float cr = Ct[(pp * 128 + p) * 2], ci = Ct[(pp * 128 + p) * 2 + 1];
      v = par == 0 ? (cq == 0 ? cr : -ci) : (cq == 0 ? ci : cr);
    } else {
      int qq = (c - 256) >> 1, cq = c & 1;
      float dr = Dt[(qq * 128 + p) * 2], di = Dt[(qq * 128 + p) * 2 + 1];
      v = par == 0 ? (cq == 0 ? dr : -di) : (cq == 0 ? di : dr);
    }
    unsigned short h = f2bf(v);
    Mch[r * 512 + c] = h; Mcl[r * 512 + c] = f2bf(v - bf2f(h));
  }
}

// ---------------- register FFT-2048: radix 8*8*8*4, 256 threads ----------------
#define SW(k) ((k) ^ (((k) >> 4) & 31))

template <int SGN>
__device__ __forceinline__ void dft8(cpx a[8]) {
  cpx t0 = cadd(a[0], a[4]), u0 = csub(a[0], a[4]);
  cpx t1 = cadd(a[1], a[5]), u1 = csub(a[1], a[5]);
  cpx t2 = cadd(a[2], a[6]), u2 = csub(a[2], a[6]);
  cpx t3 = cadd(a[3], a[7]), u3 = csub(a[3], a[7]);
  cpx E0 = cadd(t0, t2), E2 = csub(t0, t2);
  cpx ju2 = mulJ<SGN>(u2);
  cpx E1 = cadd(u0, ju2), E3 = csub(u0, ju2);
  cpx O0 = cadd(t1, t3), O2 = csub(t1, t3);
  cpx ju3 = mulJ<SGN>(u3);
  cpx O1 = cadd(u1, ju3), O3 = csub(u1, ju3);
  const float r = 0.70710678118654752f;
  const float S = (float)SGN;
  cpx w1O1 = make_float2(r * (O1.x - S * O1.y), r * (O1.y + S * O1.x));
  cpx w3O3 = make_float2(r * (-O3.x - S * O3.y), r * (S * O3.x - O3.y));
  cpx jO2 = mulJ<SGN>(O2);
  a[0] = cadd(E0, O0);   a[4] = csub(E0, O0);
  a[1] = cadd(E1, w1O1); a[5] = csub(E1, w1O1);
  a[2] = cadd(E2, jO2);  a[6] = csub(E2, jO2);
  a[3] = cadd(E3, w3O3); a[7] = csub(E3, w3O3);
}

template <int SGN>
__device__ __forceinline__ void dft4(cpx b[4]) {
  cpx s0 = cadd(b[0], b[2]), d0 = csub(b[0], b[2]);
  cpx s1 = cadd(b[1], b[3]), d1 = csub(b[1], b[3]);
  cpx jd1 = mulJ<SGN>(d1);
  b[0] = cadd(s0, s1); b[2] = csub(s0, s1);
  b[1] = cadd(d0, jd1); b[3] = csub(d0, jd1);
}

__device__ __forceinline__ void twid8(cpx a[8], float ang) {
  float s, c; __sincosf(ang, &s, &c);
  cpx w1 = make_float2(c, s);
  cpx w2 = cmul(w1, w1), w3 = cmul(w2, w1), w4 = cmul(w2, w2);
  cpx w5 = cmul(w3, w2), w6 = cmul(w3, w3), w7 = cmul(w4, w3);
  a[1] = cmul(a[1], w1); a[2] = cmul(a[2], w2); a[3] = cmul(a[3], w3);
  a[4] = cmul(a[4], w4); a[5] = cmul(a[5], w5); a[6] = cmul(a[6], w6);
  a[7] = cmul(a[7], w7);
}

template <int SGN>
__device__ __forceinline__ void fft2048_core(cpx a[8], cpx* __restrict__ bufA,
                                             cpx* __restrict__ bufB, int t) {
  const float S = (float)SGN;
  dft8<SGN>(a);
  twid8(a, S * (2.f * PI_F / 2048.f) * (float)t);
#pragma unroll
  for (int p = 0; p < 8; ++p) bufA[p * 264 + t] = a[p];
  __syncthreads();
  int p = t >> 5, n1 = t & 31;
#pragma unroll
  for (int j = 0; j < 8; ++j) a[j] = bufA[p * 264 + n1 + 32 * j];
  dft8<SGN>(a);
  twid8(a, S * (2.f * PI_F / 256.f) * (float)n1);
#pragma unroll
  for (int q = 0; q < 8; ++q) bufB[p * 264 + q * 33 + n1] = a[q];
  __syncthreads();
  int q = (t >> 2) & 7, n2 = t & 3;
#pragma unroll
  for (int j = 0; j < 8; ++j) a[j] = bufB[p * 264 + q * 33 + n2 + 4 * j];
  dft8<SGN>(a);
  twid8(a, S * (2.f * PI_F / 32.f) * (float)n2);
#pragma unroll
  for (int d = 0; d < 8; ++d) bufA[p * 264 + q * 33 + 4 * d + n2] = a[d];
  __syncthreads();
#pragma unroll
  for (int h = 0; h < 2; ++h) {
    int d = 2 * n2 + h;
    cpx b[4];
#pragma unroll
    for (int m = 0; m < 4; ++m) b[m] = bufA[p * 264 + q * 33 + 4 * d + m];
    dft4<SGN>(b);
    int kb = p + 8 * q + 64 * d;
#pragma unroll
    for (int c = 0; c < 4; ++c) bufB[SW(kb + 512 * c)] = b[c];
  }
  __syncthreads();
}

// ---------------- forward rfft-4096 -> bf16 pair plane U[q][col] ----------------
__global__ __launch_bounds__(256) void fft_fwd_pack(const float* __restrict__ u,
                                                    unsigned int* __restrict__ Uph) {
  __shared__ cpx bufA[2112], bufB[2112];
  int t = threadIdx.x;
  int row = blockIdx.x;
  int b = row >> 7, q = row & 127;
  const cpx* src = (const cpx*)(u + (size_t)row * NL);
  cpx a[8];
#pragma unroll
  for (int j = 0; j < 8; ++j) a[j] = src[t + 256 * j];
  fft2048_core<-1>(a, bufA, bufB, t);
  unsigned int* Uh = Uph + (size_t)q * NT + (size_t)b * WB;
  auto pstore = [&](int k, float ur, float ui) { Uh[k] = packpair(ur, ui); };
#pragma unroll
  for (int r = 0; r < 4; ++r) {
    int k = t + (r << 8);
    if (k == 0) {
      cpx z0 = bufB[SW(0)];
      pstore(0, z0.x + z0.y, 0.f);
      pstore(2048, z0.x - z0.y, 0.f);
      cpx zN = bufB[SW(1024)];
      pstore(1024, zN.x, -zN.y);
    } else {
      cpx A = bufB[SW(k)];
      cpx M = bufB[SW(2048 - k)];
      float Br = M.x, Bi = -M.y;
      float sr = 0.5f * (A.x + Br), si = 0.5f * (A.y + Bi);
      float dr = 0.5f * (A.x - Br), di = 0.5f * (A.y - Bi);
      float th = (float)k * (PI_F / 2048.f);
      float sn, cs; __sincosf(th, &sn, &cs);
      float tr = cs * dr + sn * di;
      float ti = cs * di - sn * dr;
      pstore(k, sr + ti, si - tr);
      float A2r = M.x, A2i = M.y;
      float B2r = A.x, B2i = -A.y;
      float s2r = 0.5f * (A2r + B2r), s2i = 0.5f * (A2i + B2i);
      float d2r = 0.5f * (A2r - B2r), d2i = 0.5f * (A2i - B2i);
      float t2r = -cs * d2r + sn * d2i;
      float t2i = -cs * d2i - sn * d2r;
      pstore(2048 - k, s2r + t2i, s2i - t2r);
    }
  }
}

// ---------------- GEMM B-panel staging (single bf16 plane) ----------------
// LDS: [quad 0..3][col 0..127][8 ushorts]; frag = 8 consecutive ushorts (b128 read).
__device__ __forceinline__ void stageB1(const unsigned int* __restrict__ Sh,
                                        int qt, int j0, int tid,
                                        unsigned short* __restrict__ Bh) {
  int col = tid & 127, grp = tid >> 7;
#pragma unroll
  for (int gg = 0; gg < 2; ++gg) {
    int g = grp + 2 * gg;
    uint4 hv;
    size_t base = (size_t)(qt + g * 4) * NT + j0 + col;
    hv.x = Sh[base];
    hv.y = Sh[base + NT];
    hv.z = Sh[base + 2 * NT];
    hv.w = Sh[base + 3 * NT];
    *(uint4*)&Bh[(g * 128 + col) * 8] = hv;
  }
}

// ---------------- GEMM1: V2 = Mb x U2 (A split hi/lo, 2 MFMA), scale, store ----------------
__global__ __launch_bounds__(256, 2) void gemm1(
    const unsigned short* __restrict__ Mbh, const unsigned short* __restrict__ Mbl,
    const unsigned int* __restrict__ Uph,
    const float* __restrict__ Lam,
    unsigned int* __restrict__ Vph) {
  __shared__ unsigned short Ah[4096], Al[4096], Bh[4096];
  int tid = threadIdx.x;
  int i0 = blockIdx.x * 128;
  int j0 = blockIdx.y * 128;
  int w = tid >> 6, lane = tid & 63, quad = lane >> 4, ln = lane & 15;
  int mw = w & 1, nw = w >> 1;
  f4 acc[4][4];
#pragma unroll
  for (int mt = 0; mt < 4; ++mt)
#pragma unroll
    for (int nt = 0; nt < 4; ++nt) acc[mt][nt] = (f4){0.f, 0.f, 0.f, 0.f};

  for (int kt = 0; kt < 256; kt += 32) {
    __syncthreads();
#pragma unroll
    for (int r = 0; r < 2; ++r) {
      int j = tid + 256 * r; int m = j >> 2, cch = j & 3;
      int slot = (m * 4 + (cch ^ (m & 3))) * 8;
      size_t go = (size_t)(i0 + m) * 256 + kt + cch * 8;
      *(uint4*)&Ah[slot] = *(const uint4*)&Mbh[go];
      *(uint4*)&Al[slot] = *(const uint4*)&Mbl[go];
    }
    stageB1(Uph, kt >> 1, j0, tid, Bh);
    __syncthreads();
    bf8v ah[4], al[4], bh[4];
#pragma unroll
    for (int mt = 0; mt < 4; ++mt) {
      int m = mw * 64 + mt * 16 + ln;
      int off = (m * 4 + (quad ^ (m & 3))) * 8;
      ah[mt] = *(const bf8v*)&Ah[off];
      al[mt] = *(const bf8v*)&Al[off];
    }
#pragma unroll
    for (int nt = 0; nt < 4; ++nt) {
      int off = (quad * 128 + nw * 64 + nt * 16 + ln) * 8;
      bh[nt] = *(const bf8v*)&Bh[off];
    }
#pragma unroll
    for (int mt = 0; mt < 4; ++mt)
#pragma unroll
      for (int nt = 0; nt < 4; ++nt) {
        acc[mt][nt] = MFMA16(ah[mt], bh[nt], acc[mt][nt]);
        acc[mt][nt] = MFMA16(al[mt], bh[nt], acc[mt][nt]);
      }
  }
#pragma unroll
  for (int mt = 0; mt < 4; ++mt) {
    int r0 = i0 + mw * 64 + mt * 16 + quad * 4;
    int p0 = r0 >> 1;
    float2 lam0 = ((const float2*)Lam)[p0];
    float2 lam1 = ((const float2*)Lam)[p0 + 1];
#pragma unroll
    for (int nt = 0; nt < 4; ++nt) {
      int col = j0 + nw * 64 + nt * 16 + ln;
      int bb = col / WB; int l = col - bb * WB;
      float omega = (float)l * (PI_F / 2048.f);
      f4 a = acc[mt][nt];
      float dx0 = -lam0.x, dy0 = omega - lam0.y;
      float inv0 = 1.f / (dx0 * dx0 + dy0 * dy0);
      float kr0 = dx0 * inv0, ki0 = -dy0 * inv0;
      float v0r = kr0 * a[0] - ki0 * a[1];
      float v0i = kr0 * a[1] + ki0 * a[0];
      float dx1 = -lam1.x, dy1 = omega - lam1.y;
      float inv1 = 1.f / (dx1 * dx1 + dy1 * dy1);
      float kr1 = dx1 * inv1, ki1 = -dy1 * inv1;
      float v1r = kr1 * a[2] - ki1 * a[3];
      float v1i = kr1 * a[3] + ki1 * a[2];
      Vph[(size_t)p0 * NT + col] = packpair(v0r, v0i);
      Vph[(size_t)(p0 + 1) * NT + col] = packpair(v1r, v1i);
    }
  }
}

// ---------------- GEMM2: Y2 = Mc x [V2'; U2], float2 pair output Y[h][col] ----------------
__global__ __launch_bounds__(256, 2) void gemm2(
    const unsigned short* __restrict__ Mch, const unsigned short* __restrict__ Mcl,
    const unsigned int* __restrict__ Vph, const unsigned int* __restrict__ Uph,
    float2* __restrict__ Yp) {
  __shared__ unsigned short Ah[4096], Al[4096], Bh[4096];
  int tid = threadIdx.x;
  int i0 = blockIdx.x * 128;
  int j0 = blockIdx.y * 128;
  int w = tid >> 6, lane = tid & 63, quad = lane >> 4, ln = lane & 15;
  int mw = w & 1, nw = w >> 1;
  f4 acc[4][4];
#pragma unroll
  for (int mt = 0; mt < 4; ++mt)
#pragma unroll
    for (int nt = 0; nt < 4; ++nt) acc[mt][nt] = (f4){0.f, 0.f, 0.f, 0.f};

  for (int kt = 0; kt < 512; kt += 32) {
    __syncthreads();
#pragma unroll
    for (int r = 0; r < 2; ++r) {
      int j = tid + 256 * r; int m = j >> 2, cch = j & 3;
      int slot = (m * 4 + (cch ^ (m & 3))) * 8;
      size_t go = (size_t)(i0 + m) * 512 + kt + cch * 8;
      *(uint4*)&Ah[slot] = *(const uint4*)&Mch[go];
      *(uint4*)&Al[slot] = *(const uint4*)&Mcl[go];
    }
    if (kt < 256) stageB1(Vph, kt >> 1, j0, tid, Bh);
    else          stageB1(Uph, (kt - 256) >> 1, j0, tid, Bh);
    __syncthreads();
    bf8v ah[4], al[4], bh[4];
#pragma unroll
    for (int mt = 0; mt < 4; ++mt) {
      int m = mw * 64 + mt * 16 + ln;
      int off = (m * 4 + (quad ^ (m & 3))) * 8;
      ah[mt] = *(const bf8v*)&Ah[off];
      al[mt] = *(const bf8v*)&Al[off];
    }
#pragma unroll
    for (int nt = 0; nt < 4; ++nt) {
      int off = (quad * 128 + nw * 64 + nt * 16 + ln) * 8;
      bh[nt] = *(const bf8v*)&Bh[off];
    }
#pragma unroll
    for (int mt = 0; mt < 4; ++mt)
#pragma unroll
      for (int nt = 0; nt < 4; ++nt) {
        acc[mt][nt] = MFMA16(ah[mt], bh[nt], acc[mt][nt]);
        acc[mt][nt] = MFMA16(al[mt], bh[nt], acc[mt][nt]);
      }
  }
#pragma unroll
  for (int mt = 0; mt < 4; ++mt) {
    int r0 = i0 + mw * 64 + mt * 16 + quad * 4;
    int h0 = r0 >> 1;
#pragma unroll
    for (int nt = 0; nt < 4; ++nt) {
      int col = j0 + nw * 64 + nt * 16 + ln;
      f4 a = acc[mt][nt];
      Yp[(size_t)h0 * NT + col] = make_float2(a[0], a[1]);
      Yp[(size_t)(h0 + 1) * NT + col] = make_float2(a[2], a[3]);
    }
  }
}

// ---------------- inverse rfft-4096 from float2 pair planes, fused exact GELU ----------------
__global__ __launch_bounds__(256) void fft_inv_gelu_pl(const float2* __restrict__ Yp,
                                                       float* __restrict__ out) {
  __shared__ cpx bufA[2112], bufB[2112];
  int t = threadIdx.x;
  int row = blockIdx.x;
  int b = row >> 7, h = row & 127;
  const float2* Yrow = Yp + (size_t)h * NT + (size_t)b * WB;
#pragma unroll
  for (int r = 0; r < 4; ++r) {
    int k = t + (r << 8);
    if (k == 0) {
      float y0 = Yrow[0].x;     // Im discarded (pocketfft irfft semantics)
      float yN = Yrow[2048].x;
      bufB[SW(0)] = make_float2(0.5f * (y0 + yN), 0.5f * (y0 - yN));
      float2 z = Yrow[1024];
      bufB[SW(1024)] = make_float2(z.x, -z.y);
    } else {
      float2 A = Yrow[k];
      float2 M = Yrow[2048 - k];
      float Br = M.x, Bi = -M.y;
      float sr = 0.5f * (A.x + Br), si = 0.5f * (A.y + Bi);
      float dr = 0.5f * (A.x - Br), di = 0.5f * (A.y - Bi);
      float th = (float)k * (PI_F / 2048.f);
      float sn, cs; __sincosf(th, &sn, &cs);
      float e1 = cs * di + sn * dr;
      float e2 = cs * dr - sn * di;
      bufB[SW(k)] = make_float2(sr - e1, si + e2);
      bufB[SW(2048 - k)] = make_float2(sr + e1, -si + e2);
    }
  }
  __syncthreads();
  cpx a[8];
#pragma unroll
  for (int j = 0; j < 8; ++j) a[j] = bufB[SW(t + 256 * j)];
  fft2048_core<1>(a, bufA, bufB, t);
  float2* dst = (float2*)(out + (size_t)row * NL);
  const float sc = 1.f / 2048.f;
#pragma unroll
  for (int r = 0; r < 8; ++r) {
    int n = t + (r << 8);
    cpx z = bufB[SW(n)];
    dst[n] = make_float2(gelu_exact(z.x * sc), gelu_exact(z.y * sc));
  }
}

// ================= FALLBACK (used only if ws too small) =================
__global__ __launch_bounds__(256) void fb_fft_fwd(const float* __restrict__ u,
                                                  cpx* __restrict__ U) {
  __shared__ cpx bufA[2112], bufB[2112];
  int t = threadIdx.x;
  int row = blockIdx.x;
  const cpx* src = (const cpx*)(u + (size_t)row * NL);
  cpx a[8];
#pragma unroll
  for (int j = 0; j < 8; ++j) a[j] = src[t + 256 * j];
  fft2048_core<-1>(a, bufA, bufB, t);
  cpx* Urow = U + (size_t)row * LF;
#pragma unroll
  for (int r = 0; r < 4; ++r) {
    int k = t + (r << 8);
    if (k == 0) {
      cpx z0 = bufB[SW(0)];
      Urow[0] = make_float2(z0.x + z0.y, 0.f);
      Urow[2048] = make_float2(z0.x - z0.y, 0.f);
      cpx zN = bufB[SW(1024)];
      Urow[1024] = make_float2(zN.x, -zN.y);
    } else {
      cpx A = bufB[SW(k)];
      cpx M = bufB[SW(2048 - k)];
      float Br = M.x, Bi = -M.y;
      float sr = 0.5f * (A.x + Br), si = 0.5f * (A.y + Bi);
      float dr = 0.5f * (A.x - Br), di = 0.5f * (A.y - Bi);
      float th = (float)k * (PI_F / 2048.f);
      float sn, cs; __sincosf(th, &sn, &cs);
      float tr = cs * dr + sn * di;
      float ti = cs * di - sn * dr;
      Urow[k] = make_float2(sr + ti, si - tr);
      float A2r = M.x, A2i = M.y;
      float B2r = A.x, B2i = -A.y;
      float s2r = 0.5f * (A2r + B2r), s2i = 0.5f * (A2i + B2i);
      float d2r = 0.5f * (A2r - B2r), d2i = 0.5f * (A2i - B2i);
      float t2r = -cs * d2r + sn * d2i;
      float t2i = -cs * d2i - sn * d2r;
      Urow[2048 - k] = make_float2(s2r + t2i, s2i - t2r);
    }
  }
}

__device__ __forceinline__ void ld4(float4 d[4], const float4* __restrict__ p) {
#pragma unroll
  for (int kk = 0; kk < 4; ++kk) d[kk] = p[kk];
}
__device__ __forceinline__ void cmac4(const float4 m[4], float xr, float xi,
                                      float ar[8], float ai[8]) {
#pragma unroll
  for (int kk = 0; kk < 4; ++kk) {
    float4 v = m[kk];
    ar[2 * kk]     = fmaf(v.x, xr, fmaf(-v.y, xi, ar[2 * kk]));
    ai[2 * kk]     = fmaf(v.x, xi, fmaf( v.y, xr, ai[2 * kk]));
    ar[2 * kk + 1] = fmaf(v.z, xr, fmaf(-v.w, xi, ar[2 * kk + 1]));
    ai[2 * kk + 1] = fmaf(v.z, xi, fmaf( v.w, xr, ai[2 * kk + 1]));
  }
}

__global__ __launch_bounds__(256) void fb_mix(
    const cpx* __restrict__ U,
    const float* __restrict__ Bt, const float* __restrict__ Ct,
    const float* __restrict__ Dt, const float* __restrict__ Lam,
    cpx* __restrict__ Y) {
  __shared__ cpx sU[128][17], sV[128][17];
  int tid = threadIdx.x;
  int b = blockIdx.y;
  size_t ub = (size_t)b * NH * LF;
  if (blockIdx.x == 128) {
    int t = tid;
    if (t < 128) sU[t][0] = U[ub + (size_t)t * LF + 2048];
    __syncthreads();
    if (t < 128) {
      float ar = 0.f, ai = 0.f;
      for (int q = 0; q < 128; ++q) {
        float ur = sU[q][0].x, ui = sU[q][0].y;
        float br = Bt[(q * 128 + t) * 2], bi = Bt[(q * 128 + t) * 2 + 1];
        ar = fmaf(br, ur, fmaf(-bi, ui, ar));
        ai = fmaf(br, ui, fmaf(bi, ur, ai));
      }
      float a = Lam[2 * t], bb = Lam[2 * t + 1];
      float dx = -a, dy = PI_F - bb;
      float inv = 1.f / (dx * dx + dy * dy);
      float kr = dx * inv, ki = -dy * inv;
      sV[t][0] = make_float2(kr * ar - ki * ai, kr * ai + ki * ar);
    }
    __syncthreads();
    if (t < 128) {
      float ar = 0.f, ai = 0.f;
      for (int q = 0; q < 128; ++q) {
        float ur = sU[q][0].x, ui = sU[q][0].y;
        float vr = sV[q][0].x, vi = sV[q][0].y;
        float cr = Ct[(q * 128 + t) * 2], ci = Ct[(q * 128 + t) * 2 + 1];
        float dr = Dt[(q * 128 + t) * 2], di = Dt[(q * 128 + t) * 2 + 1];
        ar += cr * vr - ci * vi + dr * ur - di * ui;
        ai += cr * vi + ci * vr + dr * ui + di * ur;
      }
      Y[ub + (size_t)t * LF + 2048] = make_float2(ar, ai);
    }
    return;
  }
  int lane = tid & 15, g = tid >> 4;
  int l = blockIdx.x * 16 + lane;
#pragma unroll
  for (int rep = 0; rep < 8; ++rep) {
    int q = rep * 16 + g;
    sU[q][lane] = U[ub + (size_t)q * LF + l];
  }
  __syncthreads();
  float omega = (float)l * (PI_F / 2048.f);
  float ar[8], ai[8];
  {
#pragma unroll
    for (int k = 0; k < 8; ++k) { ar[k] = 0.f; ai[k] = 0.f; }
    const float4* base = (const float4*)Bt + g * 4;
    float4 e[4], o[4];
    ld4(e, base);
#pragma unroll 1
    for (int q = 0; q < 128; q += 2) {
      ld4(o, base + (q + 1) * 64);
      cpx u0 = sU[q][lane];
      cmac4(e, u0.x, u0.y, ar, ai);
      ld4(e, base + ((q + 2) & 127) * 64);
      cpx u1 = sU[q + 1][lane];
      cmac4(o, u1.x, u1.y, ar, ai);
    }
    int p0 = g * 8;
#pragma unroll
    for (int k = 0; k < 8; ++k) {
      int p = p0 + k;
      float a = Lam[2 * p], bb = Lam[2 * p + 1];
      float dx = -a, dy = omega - bb;
      float inv = 1.f / (dx * dx + dy * dy);
      float kr = dx * inv, ki = -dy * inv;
      sV[p][lane] = make_float2(kr * ar[k] - ki * ai[k], kr * ai[k] + ki * ar[k]);
    }
  }
  __syncthreads();
  {
#pragma unroll
    for (int k = 0; k < 8; ++k) { ar[k] = 0.f; ai[k] = 0.f; }
    const float4* base = (const float4*)Ct + g * 4;
    float4 e[4], o[4];
    ld4(e, base);
#pragma unroll 1
    for (int q = 0; q < 128; q += 2) {
      ld4(o, base + (q + 1) * 64);
      cpx v0 = sV[q][lane];
      cmac4(e, v0.x, v0.y, ar, ai);
      ld4(e, base + ((q + 2) & 127) * 64);
      cpx v1 = sV[q + 1][lane];
      cmac4(o, v1.x, v1.y, ar, ai);
    }
  }
  {
    const float4* base = (const float4*)Dt + g * 4;
    float4 e[4], o[4];
    ld4(e, base);
#pragma unroll 1
    for (int q = 0; q < 128; q += 2) {
      ld4(o, base + (q + 1) * 64);
      cpx u0 = sU[q][lane];
      cmac4(e, u0.x, u0.y, ar, ai);
      ld4(e, base + ((q + 2) & 127) * 64);
      cpx u1 = sU[q + 1][lane];
      cmac4(o, u1.x, u1.y, ar, ai);
    }
  }
  int h0 = g * 8;
#pragma unroll
  for (int k = 0; k < 8; ++k) {
    Y[ub + (size_t)(h0 + k) * LF + l] = make_float2(ar[k], ai[k]);
  }
}

__global__ __launch_bounds__(256) void fb_fft_inv(const cpx* __restrict__ Y,
                                                  float* __restrict__ out) {
  __shared__ cpx bufA[2112], bufB[2112];
  int t = threadIdx.x;
  int row = blockIdx.x;
  const cpx* Yrow = Y + (size_t)row * LF;
#pragma unroll
  for (int r = 0; r < 4; ++r) {
    int k = t + (r << 8);
    if (k == 0) {
      float y0 = Yrow[0].x;
      float yN = Yrow[2048].x;
      bufB[SW(0)] = make_float2(0.5f * (y0 + yN), 0.5f * (y0 - yN));
      cpx z = Yrow[1024];
      bufB[SW(1024)] = make_float2(z.x, -z.y);
    } else {
      cpx A = Yrow[k];
      cpx M = Yrow[2048 - k];
      float Br = M.x, Bi = -M.y;
      float sr = 0.5f * (A.x + Br), si = 0.5f * (A.y + Bi);
      float dr = 0.5f * (A.x - Br), di = 0.5f * (A.y - Bi);
      float th = (float)k * (PI_F / 2048.f);
      float sn, cs; __sincosf(th, &sn, &cs);
      float e1 = cs * di + sn * dr;
      float e2 = cs * dr - sn * di;
      bufB[SW(k)] = make_float2(sr - e1, si + e2);
      bufB[SW(2048 - k)] = make_float2(sr + e1, -si + e2);
    }
  }
  __syncthreads();
  cpx a[8];
#pragma unroll
  for (int j = 0; j < 8; ++j) a[j] = bufB[SW(t + 256 * j)];
  fft2048_core<1>(a, bufA, bufB, t);
  float2* dst = (float2*)(out + (size_t)row * NL);
  const float sc = 1.f / 2048.f;
#pragma unroll
  for (int r = 0; r < 8; ++r) {
    int n = t + (r << 8);
    cpx z = bufB[SW(n)];
    dst[n] = make_float2(gelu_exact(z.x * sc), gelu_exact(z.y * sc));
  }
}

extern "C" void kernel_launch(void* const* d_in, const int* in_sizes, int n_in,
                              void* d_out, int out_size, void* d_ws, size_t ws_size,
                              hipStream_t stream) {
  const float* u   = (const float*)d_in[0];
  const float* C2  = (const float*)d_in[1];
  const float* B2  = (const float*)d_in[2];
  const float* D   = (const float*)d_in[3];
  const float* Lam = (const float*)d_in[4];
  float* out = (float*)d_out;

  const size_t PL = (size_t)128 * NT;                 // dwords per pair plane
  const size_t need = PL * 4 * 2                      // Uph, Vph
                    + PL * 8                          // Yp float2
                    + 3 * 32768 * 4                   // Bt, Ct, Dt fp32
                    + 2 * 65536 * 2 + 2 * 131072 * 2; // Mb, Mc bf16 hi/lo

  if (ws_size >= need) {
    unsigned int* Uph = (unsigned int*)d_ws;
    unsigned int* Vph = Uph + PL;
    float2* Yp = (float2*)(Vph + PL);
    float* Bt = (float*)(Yp + PL);
    float* Ct = Bt + 32768;
    float* Dt = Ct + 32768;
    unsigned short* Mbh = (unsigned short*)(Dt + 32768);
    unsigned short* Mbl = Mbh + 65536;
    unsigned short* Mch = Mbl + 65536;
    unsigned short* Mcl = Mch + 131072;

    precomp1<<<dim3(128, 3), 128, 0, stream>>>(C2, B2, D, Bt, Ct, Dt);
    pack_mats<<<256, 256, 0, stream>>>(Bt, Ct, Dt, Mbh, Mbl, Mch, Mcl);
    fft_fwd_pack<<<NB * NH, 256, 0, stream>>>(u, Uph);
    gemm1<<<dim3(2, NT / 128), 256, 0, stream>>>(Mbh, Mbl, Uph, Lam, Vph);
    gemm2<<<dim3(2, NT / 128), 256, 0, stream>>>(Mch, Mcl, Vph, Uph, Yp);
    fft_inv_gelu_pl<<<NB * NH, 256, 0, stream>>>(Yp, out);
  } else {
    float* ws = (float*)d_ws;
    const size_t nUc = (size_t)NB * NH * LF;
    cpx* U  = (cpx*)ws;
    cpx* Yf = U;
    float* Bt = ws + 2 * nUc;
    float* Ct = Bt + 32768;
    float* Dt = Ct + 32768;
    precomp1<<<dim3(128, 3), 128, 0, stream>>>(C2, B2, D, Bt, Ct, Dt);
    fb_fft_fwd<<<NB * NH, 256, 0, stream>>>(u, U);
    fb_mix<<<dim3(129, NB), 256, 0, stream>>>(U, Bt, Ct, Dt, Lam, Yf);
    fb_fft_inv<<<NB * NH, 256, 0, stream>>>(Yf, out);
  }
}

// Round 9
// 149.546 us; speedup vs baseline: 1.2499x; 1.0434x over previous
//
#include <hip/hip_runtime.h>
#include <math.h>

#define PI_F 3.14159265358979323846f
#define NB 8
#define NH 128
#define NL 4096
#define LF 2049    // NL/2 + 1
#define WB 2064    // padded per-batch column width (>=2049, mult of 16)
#define NT 16512   // WB * NB = total GEMM columns (= 258 * 64)

typedef float2 cpx;
typedef __attribute__((ext_vector_type(8))) short bf8v;   // 8 bf16 in 4 VGPRs
typedef __attribute__((ext_vector_type(4))) float f4;     // MFMA acc

#define MFMA16(a, b, c) __builtin_amdgcn_mfma_f32_16x16x32_bf16(a, b, c, 0, 0, 0)

__device__ __forceinline__ float gelu_exact(float x) {
  return 0.5f * x * (1.0f + erff(x * 0.70710678118654752f));
}
__device__ __forceinline__ unsigned short f2bf(float f) {
  unsigned int x = __float_as_uint(f);
  return (unsigned short)((x + 0x7FFFu + ((x >> 16) & 1u)) >> 16);
}
__device__ __forceinline__ float bf2f(unsigned short h) {
  return __uint_as_float((unsigned int)h << 16);
}
__device__ __forceinline__ unsigned int packpair(float re, float im) {
  return (unsigned int)f2bf(re) | ((unsigned int)f2bf(im) << 16);
}
__device__ __forceinline__ cpx cadd(cpx a, cpx b) { return make_float2(a.x + b.x, a.y + b.y); }
__device__ __forceinline__ cpx csub(cpx a, cpx b) { return make_float2(a.x - b.x, a.y - b.y); }
__device__ __forceinline__ cpx cmul(cpx a, cpx b) {
  return make_float2(fmaf(a.x, b.x, -a.y * b.y), fmaf(a.x, b.y, a.y * b.x));
}
template <int SGN>
__device__ __forceinline__ cpx mulJ(cpx a) {
  return (SGN < 0) ? make_float2(a.y, -a.x) : make_float2(-a.y, a.x);
}

// ---------------- precomp + pack fused: write Mb/Mc bf16 hi/lo directly ----------------
// which==0: B~ = Bbar F -> Mb rows 2p,2p+1.  which==1: C~ = F^-1 C -> Mc cols [0,256).
// which==2: D~ = F^-1 D F (two-phase via LDS) -> Mc cols [256,512).
__global__ __launch_bounds__(128) void precomp_pack(
    const float* __restrict__ C2, const float* __restrict__ B2,
    const float* __restrict__ D,
    unsigned short* __restrict__ Mbh, unsigned short* __restrict__ Mbl,
    unsigned short* __restrict__ Mch, unsigned short* __restrict__ Mcl) {
  __shared__ float rc[128], rs[128];
  __shared__ float sTr[128], sTi[128];
  int x = blockIdx.x, t = threadIdx.x, which = blockIdx.y;
  { float s, c; sincosf(-(2.f * PI_F / 128.f) * (float)t, &s, &c); rc[t] = c; rs[t] = s; }
  __syncthreads();
  float sr = 0.f, si = 0.f;
  if (which == 0) {
    // B~[p=x][q=t]
    for (int k = 0; k < 128; ++k) {
      int j = (k * t) & 127; float c = rc[j], s = rs[j];
      float br = B2[(x * 128 + k) * 2], bi = B2[(x * 128 + k) * 2 + 1];
      sr += br * c - bi * s; si += br * s + bi * c;
    }
    auto wr = [&](int r, int c, float v) {
      unsigned short h = f2bf(v);
      Mbh[r * 256 + c] = h; Mbl[r * 256 + c] = f2bf(v - bf2f(h));
    };
    wr(2 * x,     2 * t,     sr);  wr(2 * x,     2 * t + 1, -si);
    wr(2 * x + 1, 2 * t,     si);  wr(2 * x + 1, 2 * t + 1,  sr);
  } else if (which == 1) {
    // C~[h=t][p=x] (scaled by 1/128)
    for (int k = 0; k < 128; ++k) {
      int j = (k * t) & 127; float c = rc[j], s = -rs[j];  // e^{+i theta}
      float cr = C2[(k * 128 + x) * 2], ci = C2[(k * 128 + x) * 2 + 1];
      sr += cr * c - ci * s; si += cr * s + ci * c;
    }
    sr *= (1.f / 128.f); si *= (1.f / 128.f);
    auto wr = [&](int r, int c, float v) {
      unsigned short h = f2bf(v);
      Mch[r * 512 + c] = h; Mcl[r * 512 + c] = f2bf(v - bf2f(h));
    };
    wr(2 * t,     2 * x,     sr);  wr(2 * t,     2 * x + 1, -si);
    wr(2 * t + 1, 2 * x,     si);  wr(2 * t + 1, 2 * x + 1,  sr);
  } else {
    // phase 1: T[t][x] = sum_k D[t][k] e^{-2pi i k x/128}
    for (int k = 0; k < 128; ++k) {
      int j = (k * x) & 127; float c = rc[j], s = rs[j];
      float d = D[t * 128 + k];
      sr += d * c; si += d * s;
    }
    sTr[t] = sr; sTi[t] = si;
    __syncthreads();
    // phase 2: D~[h=t][q=x] = (1/128) sum_k e^{+2pi i k t/128} T[k][x]
    sr = 0.f; si = 0.f;
    for (int k = 0; k < 128; ++k) {
      int j = (k * t) & 127; float c = rc[j], s = -rs[j];
      sr += sTr[k] * c - sTi[k] * s;
      si += sTr[k] * s + sTi[k] * c;
    }
    sr *= (1.f / 128.f); si *= (1.f / 128.f);
    auto wr = [&](int r, int c, float v) {
      unsigned short h = f2bf(v);
      Mch[r * 512 + c] = h; Mcl[r * 512 + c] = f2bf(v - bf2f(h));
    };
    wr(2 * t,     256 + 2 * x,     sr);  wr(2 * t,     256 + 2 * x + 1, -si);
    wr(2 * t + 1, 256 + 2 * x,     si);  wr(2 * t + 1, 256 + 2 * x + 1,  sr);
  }
}

// ---------------- register FFT-2048: radix 8*8*8*4, 256 threads ----------------
#define SW(k) ((k) ^ (((k) >> 4) & 31))

template <int SGN>
__device__ __forceinline__ void dft8(cpx a[8]) {
  cpx t0 = cadd(a[0], a[4]), u0 = csub(a[0], a[4]);
  cpx t1 = cadd(a[1], a[5]), u1 = csub(a[1], a[5]);
  cpx t2 = cadd(a[2], a[6]), u2 = csub(a[2], a[6]);
  cpx t3 = cadd(a[3], a[7]), u3 = csub(a[3], a[7]);
  cpx E0 = cadd(t0, t2), E2 = csub(t0, t2);
  cpx ju2 = mulJ<SGN>(u2);
  cpx E1 = cadd(u0, ju2), E3 = csub(u0, ju2);
  cpx O0 = cadd(t1, t3), O2 = csub(t1, t3);
  cpx ju3 = mulJ<SGN>(u3);
  cpx O1 = cadd(u1, ju3), O3 = csub(u1, ju3);
  const float r = 0.70710678118654752f;
  const float S = (float)SGN;
  cpx w1O1 = make_float2(r * (O1.x - S * O1.y), r * (O1.y + S * O1.x));
  cpx w3O3 = make_float2(r * (-O3.x - S * O3.y), r * (S * O3.x - O3.y));
  cpx jO2 = mulJ<SGN>(O2);
  a[0] = cadd(E0, O0);   a[4] = csub(E0, O0);
  a[1] = cadd(E1, w1O1); a[5] = csub(E1, w1O1);
  a[2] = cadd(E2, jO2);  a[6] = csub(E2, jO2);
  a[3] = cadd(E3, w3O3); a[7] = csub(E3, w3O3);
}

template <int SGN>
__device__ __forceinline__ void dft4(cpx b[4]) {
  cpx s0 = cadd(b[0], b[2]), d0 = csub(b[0], b[2]);
  cpx s1 = cadd(b[1], b[3]), d1 = csub(b[1], b[3]);
  cpx jd1 = mulJ<SGN>(d1);
  b[0] = cadd(s0, s1); b[2] = csub(s0, s1);
  b[1] = cadd(d0, jd1); b[3] = csub(d0, jd1);
}

__device__ __forceinline__ void twid8(cpx a[8], float ang) {
  float s, c; __sincosf(ang, &s, &c);
  cpx w1 = make_float2(c, s);
  cpx w2 = cmul(w1, w1), w3 = cmul(w2, w1), w4 = cmul(w2, w2);
  cpx w5 = cmul(w3, w2), w6 = cmul(w3, w3), w7 = cmul(w4, w3);
  a[1] = cmul(a[1], w1); a[2] = cmul(a[2], w2); a[3] = cmul(a[3], w3);
  a[4] = cmul(a[4], w4); a[5] = cmul(a[5], w5); a[6] = cmul(a[6], w6);
  a[7] = cmul(a[7], w7);
}

template <int SGN>
__device__ __forceinline__ void fft2048_core(cpx a[8], cpx* __restrict__ bufA,
                                             cpx* __restrict__ bufB, int t) {
  const float S = (float)SGN;
  dft8<SGN>(a);
  twid8(a, S * (2.f * PI_F / 2048.f) * (float)t);
#pragma unroll
  for (int p = 0; p < 8; ++p) bufA[p * 264 + t] = a[p];
  __syncthreads();
  int p = t >> 5, n1 = t & 31;
#pragma unroll
  for (int j = 0; j < 8; ++j) a[j] = bufA[p * 264 + n1 + 32 * j];
  dft8<SGN>(a);
  twid8(a, S * (2.f * PI_F / 256.f) * (float)n1);
#pragma unroll
  for (int q = 0; q < 8; ++q) bufB[p * 264 + q * 33 + n1] = a[q];
  __syncthreads();
  int q = (t >> 2) & 7, n2 = t & 3;
#pragma unroll
  for (int j = 0; j < 8; ++j) a[j] = bufB[p * 264 + q * 33 + n2 + 4 * j];
  dft8<SGN>(a);
  twid8(a, S * (2.f * PI_F / 32.f) * (float)n2);
#pragma unroll
  for (int d = 0; d < 8; ++d) bufA[p * 264 + q * 33 + 4 * d + n2] = a[d];
  __syncthreads();
#pragma unroll
  for (int h = 0; h < 2; ++h) {
    int d = 2 * n2 + h;
    cpx b[4];
#pragma unroll
    for (int m = 0; m < 4; ++m) b[m] = bufA[p * 264 + q * 33 + 4 * d + m];
    dft4<SGN>(b);
    int kb = p + 8 * q + 64 * d;
#pragma unroll
    for (int c = 0; c < 4; ++c) bufB[SW(kb + 512 * c)] = b[c];
  }
  __syncthreads();
}

// ---------------- forward rfft-4096 -> bf16 pair plane U[q][col] ----------------
__global__ __launch_bounds__(256) void fft_fwd_pack(const float* __restrict__ u,
                                                    unsigned int* __restrict__ Uph) {
  __shared__ cpx bufA[2112], bufB[2112];
  int t = threadIdx.x;
  int row = blockIdx.x;
  int b = row >> 7, q = row & 127;
  const cpx* src = (const cpx*)(u + (size_t)row * NL);
  cpx a[8];
#pragma unroll
  for (int j = 0; j < 8; ++j) a[j] = src[t + 256 * j];
  fft2048_core<-1>(a, bufA, bufB, t);
  unsigned int* Uh = Uph + (size_t)q * NT + (size_t)b * WB;
  auto pstore = [&](int k, float ur, float ui) { Uh[k] = packpair(ur, ui); };
#pragma unroll
  for (int r = 0; r < 4; ++r) {
    int k = t + (r << 8);
    if (k == 0) {
      cpx z0 = bufB[SW(0)];
      pstore(0, z0.x + z0.y, 0.f);
      pstore(2048, z0.x - z0.y, 0.f);
      cpx zN = bufB[SW(1024)];
      pstore(1024, zN.x, -zN.y);
    } else {
      cpx A = bufB[SW(k)];
      cpx M = bufB[SW(2048 - k)];
      float Br = M.x, Bi = -M.y;
      float sr = 0.5f * (A.x + Br), si = 0.5f * (A.y + Bi);
      float dr = 0.5f * (A.x - Br), di = 0.5f * (A.y - Bi);
      float th = (float)k * (PI_F / 2048.f);
      float sn, cs; __sincosf(th, &sn, &cs);
      float tr = cs * dr + sn * di;
      float ti = cs * di - sn * dr;
      pstore(k, sr + ti, si - tr);
      float A2r = M.x, A2i = M.y;
      float B2r = A.x, B2i = -A.y;
      float s2r = 0.5f * (A2r + B2r), s2i = 0.5f * (A2i + B2i);
      float d2r = 0.5f * (A2r - B2r), d2i = 0.5f * (A2i - B2i);
      float t2r = -cs * d2r + sn * d2i;
      float t2i = -cs * d2i - sn * d2r;
      pstore(2048 - k, s2r + t2i, s2i - t2r);
    }
  }
}

// ---------------- fused GEMM: V = k.(Mb U), Y = Mc [V; U]; V lives in LDS ----------------
// Block owns 64 cols and ALL 256 rows; 4 waves stacked on M; acc[4][4]; BK=32.
// LDS: Ah/Al 16 KB each (256x32), Bh 4 KB, Vl 32 KB (B-frag layout) = 68 KB -> 2 blk/CU.
__global__ __launch_bounds__(256, 2) void gemm_fused(
    const unsigned short* __restrict__ Mbh, const unsigned short* __restrict__ Mbl,
    const unsigned short* __restrict__ Mch, const unsigned short* __restrict__ Mcl,
    const unsigned int* __restrict__ Uph,
    const float* __restrict__ Lam,
    float2* __restrict__ Yp) {
  __shared__ unsigned short Ah[8192], Al[8192];  // 256 rows x 32 k, XOR-swizzled
  __shared__ unsigned short Bh[2048];            // 4 chunks x 64 cols x 8
  __shared__ unsigned int Vl[8192];              // 32 chunks x 64 cols x 4 dwords
  int tid = threadIdx.x;
  int j0 = blockIdx.x * 64;
  int w = tid >> 6, lane = tid & 63, quad = lane >> 4, ln = lane & 15;
  int colB = tid & 63, grpB = tid >> 6;
  f4 acc[4][4];
#pragma unroll
  for (int mt = 0; mt < 4; ++mt)
#pragma unroll
    for (int nt = 0; nt < 4; ++nt) acc[mt][nt] = (f4){0.f, 0.f, 0.f, 0.f};

  // ---- phase 1: V2(256 x 64) = Mb x U2 ----
  for (int kt = 0; kt < 256; kt += 32) {
    __syncthreads();
#pragma unroll
    for (int r = 0; r < 4; ++r) {
      int j = tid + 256 * r; int m = j >> 2, cch = j & 3;
      int slot = (m * 4 + (cch ^ (m & 3))) * 8;
      size_t go = (size_t)m * 256 + kt + cch * 8;
      *(uint4*)&Ah[slot] = *(const uint4*)&Mbh[go];
      *(uint4*)&Al[slot] = *(const uint4*)&Mbl[go];
    }
    {
      size_t base = (size_t)((kt >> 1) + grpB * 4) * NT + j0 + colB;
      uint4 hv;
      hv.x = Uph[base];          hv.y = Uph[base + NT];
      hv.z = Uph[base + 2 * NT]; hv.w = Uph[base + 3 * NT];
      *(uint4*)&Bh[(grpB * 64 + colB) * 8] = hv;
    }
    __syncthreads();
    bf8v ah[4], al[4], bh[4];
#pragma unroll
    for (int mt = 0; mt < 4; ++mt) {
      int m = w * 64 + mt * 16 + ln;
      int off = (m * 4 + (quad ^ (m & 3))) * 8;
      ah[mt] = *(const bf8v*)&Ah[off];
      al[mt] = *(const bf8v*)&Al[off];
    }
#pragma unroll
    for (int nt = 0; nt < 4; ++nt)
      bh[nt] = *(const bf8v*)&Bh[(quad * 64 + nt * 16 + ln) * 8];
#pragma unroll
    for (int mt = 0; mt < 4; ++mt)
#pragma unroll
      for (int nt = 0; nt < 4; ++nt) {
        acc[mt][nt] = MFMA16(ah[mt], bh[nt], acc[mt][nt]);
        acc[mt][nt] = MFMA16(al[mt], bh[nt], acc[mt][nt]);
      }
  }
  // phase-1 epilogue: Cauchy scale, V -> LDS (B-frag layout: [chunk p>>2][col][dword p&3])
  __syncthreads();
#pragma unroll
  for (int mt = 0; mt < 4; ++mt) {
    int r0 = w * 64 + mt * 16 + quad * 4;
    int p0 = r0 >> 1;   // even
    float2 lam0 = ((const float2*)Lam)[p0];
    float2 lam1 = ((const float2*)Lam)[p0 + 1];
#pragma unroll
    for (int nt = 0; nt < 4; ++nt) {
      int col = nt * 16 + ln;
      int gcol = j0 + col;
      int bb = gcol / WB; int l = gcol - bb * WB;
      float omega = (float)l * (PI_F / 2048.f);
      f4 a = acc[mt][nt];
      float dx0 = -lam0.x, dy0 = omega - lam0.y;
      float inv0 = 1.f / (dx0 * dx0 + dy0 * dy0);
      float kr0 = dx0 * inv0, ki0 = -dy0 * inv0;
      float v0r = kr0 * a[0] - ki0 * a[1];
      float v0i = kr0 * a[1] + ki0 * a[0];
      float dx1 = -lam1.x, dy1 = omega - lam1.y;
      float inv1 = 1.f / (dx1 * dx1 + dy1 * dy1);
      float kr1 = dx1 * inv1, ki1 = -dy1 * inv1;
      float v1r = kr1 * a[2] - ki1 * a[3];
      float v1i = kr1 * a[3] + ki1 * a[2];
      int gc = (p0 >> 2) * 64 + col;
      Vl[gc * 4 + (p0 & 3)] = packpair(v0r, v0i);
      Vl[gc * 4 + ((p0 + 1) & 3)] = packpair(v1r, v1i);
    }
  }
  __syncthreads();

  // ---- phase 2: Y2(256 x 64) = Mc x [V2'; U2] ----
#pragma unroll
  for (int mt = 0; mt < 4; ++mt)
#pragma unroll
    for (int nt = 0; nt < 4; ++nt) acc[mt][nt] = (f4){0.f, 0.f, 0.f, 0.f};
  const unsigned short* Vs = (const unsigned short*)Vl;
  for (int kt = 0; kt < 512; kt += 32) {
    __syncthreads();
#pragma unroll
    for (int r = 0; r < 4; ++r) {
      int j = tid + 256 * r; int m = j >> 2, cch = j & 3;
      int slot = (m * 4 + (cch ^ (m & 3))) * 8;
      size_t go = (size_t)m * 512 + kt + cch * 8;
      *(uint4*)&Ah[slot] = *(const uint4*)&Mch[go];
      *(uint4*)&Al[slot] = *(const uint4*)&Mcl[go];
    }
    if (kt >= 256) {
      size_t base = (size_t)(((kt - 256) >> 1) + grpB * 4) * NT + j0 + colB;
      uint4 hv;
      hv.x = Uph[base];          hv.y = Uph[base + NT];
      hv.z = Uph[base + 2 * NT]; hv.w = Uph[base + 3 * NT];
      *(uint4*)&Bh[(grpB * 64 + colB) * 8] = hv;
    }
    __syncthreads();
    bf8v ah[4], al[4], bh[4];
#pragma unroll
    for (int mt = 0; mt < 4; ++mt) {
      int m = w * 64 + mt * 16 + ln;
      int off = (m * 4 + (quad ^ (m & 3))) * 8;
      ah[mt] = *(const bf8v*)&Ah[off];
      al[mt] = *(const bf8v*)&Al[off];
    }
    if (kt < 256) {
#pragma unroll
      for (int nt = 0; nt < 4; ++nt)
        bh[nt] = *(const bf8v*)&Vs[(((kt >> 3) + quad) * 64 + nt * 16 + ln) * 8];
    } else {
#pragma unroll
      for (int nt = 0; nt < 4; ++nt)
        bh[nt] = *(const bf8v*)&Bh[(quad * 64 + nt * 16 + ln) * 8];
    }
#pragma unroll
    for (int mt = 0; mt < 4; ++mt)
#pragma unroll
      for (int nt = 0; nt < 4; ++nt) {
        acc[mt][nt] = MFMA16(ah[mt], bh[nt], acc[mt][nt]);
        acc[mt][nt] = MFMA16(al[mt], bh[nt], acc[mt][nt]);
      }
  }
#pragma unroll
  for (int mt = 0; mt < 4; ++mt) {
    int r0 = w * 64 + mt * 16 + quad * 4;
    int h0 = r0 >> 1;   // even
#pragma unroll
    for (int nt = 0; nt < 4; ++nt) {
      int gcol = j0 + nt * 16 + ln;
      f4 a = acc[mt][nt];
      Yp[(size_t)h0 * NT + gcol] = make_float2(a[0], a[1]);
      Yp[(size_t)(h0 + 1) * NT + gcol] = make_float2(a[2], a[3]);
    }
  }
}

// ---------------- inverse rfft-4096 from float2 pair planes, fused exact GELU ----------------
__global__ __launch_bounds__(256) void fft_inv_gelu_pl(const float2* __restrict__ Yp,
                                                       float* __restrict__ out) {
  __shared__ cpx bufA[2112], bufB[2112];
  int t = threadIdx.x;
  int row = blockIdx.x;
  int b = row >> 7, h = row & 127;
  const float2* Yrow = Yp + (size_t)h * NT + (size_t)b * WB;
#pragma unroll
  for (int r = 0; r < 4; ++r) {
    int k = t + (r << 8);
    if (k == 0) {
      float y0 = Yrow[0].x;     // Im discarded (pocketfft irfft semantics)
      float yN = Yrow[2048].x;
      bufB[SW(0)] = make_float2(0.5f * (y0 + yN), 0.5f * (y0 - yN));
      float2 z = Yrow[1024];
      bufB[SW(1024)] = make_float2(z.x, -z.y);
    } else {
      float2 A = Yrow[k];
      float2 M = Yrow[2048 - k];
      float Br = M.x, Bi = -M.y;
      float sr = 0.5f * (A.x + Br), si = 0.5f * (A.y + Bi);
      float dr = 0.5f * (A.x - Br), di = 0.5f * (A.y - Bi);
      float th = (float)k * (PI_F / 2048.f);
      float sn, cs; __sincosf(th, &sn, &cs);
      float e1 = cs * di + sn * dr;
      float e2 = cs * dr - sn * di;
      bufB[SW(k)] = make_float2(sr - e1, si + e2);
      bufB[SW(2048 - k)] = make_float2(sr + e1, -si + e2);
    }
  }
  __syncthreads();
  cpx a[8];
#pragma unroll
  for (int j = 0; j < 8; ++j) a[j] = bufB[SW(t + 256 * j)];
  fft2048_core<1>(a, bufA, bufB, t);
  float2* dst = (float2*)(out + (size_t)row * NL);
  const float sc = 1.f / 2048.f;
#pragma unroll
  for (int r = 0; r < 8; ++r) {
    int n = t + (r << 8);
    cpx z = bufB[SW(n)];
    dst[n] = make_float2(gelu_exact(z.x * sc), gelu_exact(z.y * sc));
  }
}

// ================= FALLBACK (fp32 path, used only if ws too small) =================
__global__ __launch_bounds__(128) void fb_precomp(
    const float* __restrict__ C2, const float* __restrict__ B2,
    const float* __restrict__ D,
    float* __restrict__ Bt, float* __restrict__ Ct, float* __restrict__ Dt) {
  __shared__ float rc[128], rs[128];
  __shared__ float sTr[128], sTi[128];
  int x = blockIdx.x, t = threadIdx.x, which = blockIdx.y;
  { float s, c; sincosf(-(2.f * PI_F / 128.f) * (float)t, &s, &c); rc[t] = c; rs[t] = s; }
  __syncthreads();
  float sr = 0.f, si = 0.f;
  if (which == 0) {
    for (int k = 0; k < 128; ++k) {
      int j = (k * t) & 127; float c = rc[j], s = rs[j];
      float br = B2[(x * 128 + k) * 2], bi = B2[(x * 128 + k) * 2 + 1];
      sr += br * c - bi * s; si += br * s + bi * c;
    }
    Bt[(t * 128 + x) * 2] = sr; Bt[(t * 128 + x) * 2 + 1] = si;
  } else if (which == 1) {
    for (int k = 0; k < 128; ++k) {
      int j = (k * t) & 127; float c = rc[j], s = -rs[j];
      float cr = C2[(k * 128 + x) * 2], ci = C2[(k * 128 + x) * 2 + 1];
      sr += cr * c - ci * s; si += cr * s + ci * c;
    }
    Ct[(x * 128 + t) * 2] = sr * (1.f / 128.f);
    Ct[(x * 128 + t) * 2 + 1] = si * (1.f / 128.f);
  } else {
    for (int k = 0; k < 128; ++k) {
      int j = (k * x) & 127; float c = rc[j], s = rs[j];
      float d = D[t * 128 + k];
      sr += d * c; si += d * s;
    }
    sTr[t] = sr; sTi[t] = si;
    __syncthreads();
    sr = 0.f; si = 0.f;
    for (int k = 0; k < 128; ++k) {
      int j = (k * t) & 127; float c = rc[j], s = -rs[j];
      sr += sTr[k] * c - sTi[k] * s;
      si += sTr[k] * s + sTi[k] * c;
    }
    Dt[(x * 128 + t) * 2] = sr * (1.f / 128.f);
    Dt[(x * 128 + t) * 2 + 1] = si * (1.f / 128.f);
  }
}

__global__ __launch_bounds__(256) void fb_fft_fwd(const float* __restrict__ u,
                                                  cpx* __restrict__ U) {
  __shared__ cpx bufA[2112], bufB[2112];
  int t = threadIdx.x;
  int row = blockIdx.x;
  const cpx* src = (const cpx*)(u + (size_t)row * NL);
  cpx a[8];
#pragma unroll
  for (int j = 0; j < 8; ++j) a[j] = src[t + 256 * j];
  fft2048_core<-1>(a, bufA, bufB, t);
  cpx* Urow = U + (size_t)row * LF;
#pragma unroll
  for (int r = 0; r < 4; ++r) {
    int k = t + (r << 8);
    if (k == 0) {
      cpx z0 = bufB[SW(0)];
      Urow[0] = make_float2(z0.x + z0.y, 0.f);
      Urow[2048] = make_float2(z0.x - z0.y, 0.f);
      cpx zN = bufB[SW(1024)];
      Urow[1024] = make_float2(zN.x, -zN.y);
    } else {
      cpx A = bufB[SW(k)];
      cpx M = bufB[SW(2048 - k)];
      float Br = M.x, Bi = -M.y;
      float sr = 0.5f * (A.x + Br), si = 0.5f * (A.y + Bi);
      float dr = 0.5f * (A.x - Br), di = 0.5f * (A.y - Bi);
      float th = (float)k * (PI_F / 2048.f);
      float sn, cs; __sincosf(th, &sn, &cs);
      float tr = cs * dr + sn * di;
      float ti = cs * di - sn * dr;
      Urow[k] = make_float2(sr + ti, si - tr);
      float A2r = M.x, A2i = M.y;
      float B2r = A.x, B2i = -A.y;
      float s2r = 0.5f * (A2r + B2r), s2i = 0.5f * (A2i + B2i);
      float d2r = 0.5f * (A2r - B2r), d2i = 0.5f * (A2i - B2i);
      float t2r = -cs * d2r + sn * d2i;
      float t2i = -cs * d2i - sn * d2r;
      Urow[2048 - k] = make_float2(s2r + t2i, s2i - t2r);
    }
  }
}

__device__ __forceinline__ void ld4(float4 d[4], const float4* __restrict__ p) {
#pragma unroll
  for (int kk = 0; kk < 4; ++kk) d[kk] = p[kk];
}
__device__ __forceinline__ void cmac4(const float4 m[4], float xr, float xi,
                                      float ar[8], float ai[8]) {
#pragma unroll
  for (int kk = 0; kk < 4; ++kk) {
    float4 v = m[kk];
    ar[2 * kk]     = fmaf(v.x, xr, fmaf(-v.y, xi, ar[2 * kk]));
    ai[2 * kk]     = fmaf(v.x, xi, fmaf( v.y, xr, ai[2 * kk]));
    ar[2 * kk + 1] = fmaf(v.z, xr, fmaf(-v.w, xi, ar[2 * kk + 1]));
    ai[2 * kk + 1] = fmaf(v.z, xi, fmaf( v.w, xr, ai[2 * kk + 1]));
  }
}

__global__ __launch_bounds__(256) void fb_mix(
    const cpx* __restrict__ U,
    const float* __restrict__ Bt, const float* __restrict__ Ct,
    const float* __restrict__ Dt, const float* __restrict__ Lam,
    cpx* __restrict__ Y) {
  __shared__ cpx sU[128][17], sV[128][17];
  int tid = threadIdx.x;
  int b = blockIdx.y;
  size_t ub = (size_t)b * NH * LF;
  if (blockIdx.x == 128) {
    int t = tid;
    if (t < 128) sU[t][0] = U[ub + (size_t)t * LF + 2048];
    __syncthreads();
    if (t < 128) {
      float ar = 0.f, ai = 0.f;
      for (int q = 0; q < 128; ++q) {
        float ur = sU[q][0].x, ui = sU[q][0].y;
        float br = Bt[(q * 128 + t) * 2], bi = Bt[(q * 128 + t) * 2 + 1];
        ar = fmaf(br, ur, fmaf(-bi, ui, ar));
        ai = fmaf(br, ui, fmaf(bi, ur, ai));
      }
      float a = Lam[2 * t], bb = Lam[2 * t + 1];
      float dx = -a, dy = PI_F - bb;
      float inv = 1.f / (dx * dx + dy * dy);
      float kr = dx * inv, ki = -dy * inv;
      sV[t][0] = make_float2(kr * ar - ki * ai, kr * ai + ki * ar);
    }
    __syncthreads();
    if (t < 128) {
      float ar = 0.f, ai = 0.f;
      for (int q = 0; q < 128; ++q) {
        float ur = sU[q][0].x, ui = sU[q][0].y;
        float vr = sV[q][0].x, vi = sV[q][0].y;
        float cr = Ct[(q * 128 + t) * 2], ci = Ct[(q * 128 + t) * 2 + 1];
        float dr = Dt[(q * 128 + t) * 2], di = Dt[(q * 128 + t) * 2 + 1];
        ar += cr * vr - ci * vi + dr * ur - di * ui;
        ai += cr * vi + ci * vr + dr * ui + di * ur;
      }
      Y[ub + (size_t)t * LF + 2048] = make_float2(ar, ai);
    }
    return;
  }
  int lane = tid & 15, g = tid >> 4;
  int l = blockIdx.x * 16 + lane;
#pragma unroll
  for (int rep = 0; rep < 8; ++rep) {
    int q = rep * 16 + g;
    sU[q][lane] = U[ub + (size_t)q * LF + l];
  }
  __syncthreads();
  float omega = (float)l * (PI_F / 2048.f);
  float ar[8], ai[8];
  {
#pragma unroll
    for (int k = 0; k < 8; ++k) { ar[k] = 0.f; ai[k] = 0.f; }
    const float4* base = (const float4*)Bt + g * 4;
    float4 e[4], o[4];
    ld4(e, base);
#pragma unroll 1
    for (int q = 0; q < 128; q += 2) {
      ld4(o, base + (q + 1) * 64);
      cpx u0 = sU[q][lane];
      cmac4(e, u0.x, u0.y, ar, ai);
      ld4(e, base + ((q + 2) & 127) * 64);
      cpx u1 = sU[q + 1][lane];
      cmac4(o, u1.x, u1.y, ar, ai);
    }
    int p0 = g * 8;
#pragma unroll
    for (int k = 0; k < 8; ++k) {
      int p = p0 + k;
      float a = Lam[2 * p], bb = Lam[2 * p + 1];
      float dx = -a, dy = omega - bb;
      float inv = 1.f / (dx * dx + dy * dy);
      float kr = dx * inv, ki = -dy * inv;
      sV[p][lane] = make_float2(kr * ar[k] - ki * ai[k], kr * ai[k] + ki * ar[k]);
    }
  }
  __syncthreads();
  {
#pragma unroll
    for (int k = 0; k < 8; ++k) { ar[k] = 0.f; ai[k] = 0.f; }
    const float4* base = (const float4*)Ct + g * 4;
    float4 e[4], o[4];
    ld4(e, base);
#pragma unroll 1
    for (int q = 0; q < 128; q += 2) {
      ld4(o, base + (q + 1) * 64);
      cpx v0 = sV[q][lane];
      cmac4(e, v0.x, v0.y, ar, ai);
      ld4(e, base + ((q + 2) & 127) * 64);
      cpx v1 = sV[q + 1][lane];
      cmac4(o, v1.x, v1.y, ar, ai);
    }
  }
  {
    const float4* base = (const float4*)Dt + g * 4;
    float4 e[4], o[4];
    ld4(e, base);
#pragma unroll 1
    for (int q = 0; q < 128; q += 2) {
      ld4(o, base + (q + 1) * 64);
      cpx u0 = sU[q][lane];
      cmac4(e, u0.x, u0.y, ar, ai);
      ld4(e, base + ((q + 2) & 127) * 64);
      cpx u1 = sU[q + 1][lane];
      cmac4(o, u1.x, u1.y, ar, ai);
    }
  }
  int h0 = g * 8;
#pragma unroll
  for (int k = 0; k < 8; ++k) {
    Y[ub + (size_t)(h0 + k) * LF + l] = make_float2(ar[k], ai[k]);
  }
}

__global__ __launch_bounds__(256) void fb_fft_inv(const cpx* __restrict__ Y,
                                                  float* __restrict__ out) {
  __shared__ cpx bufA[2112], bufB[2112];
  int t = threadIdx.x;
  int row = blockIdx.x;
  const cpx* Yrow = Y + (size_t)row * LF;
#pragma unroll
  for (int r = 0; r < 4; ++r) {
    int k = t + (r << 8);
    if (k == 0) {
      float y0 = Yrow[0].x;
      float yN = Yrow[2048].x;
      bufB[SW(0)] = make_float2(0.5f * (y0 + yN), 0.5f * (y0 - yN));
      cpx z = Yrow[1024];
      bufB[SW(1024)] = make_float2(z.x, -z.y);
    } else {
      cpx A = Yrow[k];
      cpx M = Yrow[2048 - k];
      float Br = M.x, Bi = -M.y;
      float sr = 0.5f * (A.x + Br), si = 0.5f * (A.y + Bi);
      float dr = 0.5f * (A.x - Br), di = 0.5f * (A.y - Bi);
      float th = (float)k * (PI_F / 2048.f);
      float sn, cs; __sincosf(th, &sn, &cs);
      float e1 = cs * di + sn * dr;
      float e2 = cs * dr - sn * di;
      bufB[SW(k)] = make_float2(sr - e1, si + e2);
      bufB[SW(2048 - k)] = make_float2(sr + e1, -si + e2);
    }
  }
  __syncthreads();
  cpx a[8];
#pragma unroll
  for (int j = 0; j < 8; ++j) a[j] = bufB[SW(t + 256 * j)];
  fft2048_core<1>(a, bufA, bufB, t);
  float2* dst = (float2*)(out + (size_t)row * NL);
  const float sc = 1.f / 2048.f;
#pragma unroll
  for (int r = 0; r < 8; ++r) {
    int n = t + (r << 8);
    cpx z = bufB[SW(n)];
    dst[n] = make_float2(gelu_exact(z.x * sc), gelu_exact(z.y * sc));
  }
}

extern "C" void kernel_launch(void* const* d_in, const int* in_sizes, int n_in,
                              void* d_out, int out_size, void* d_ws, size_t ws_size,
                              hipStream_t stream) {
  const float* u   = (const float*)d_in[0];
  const float* C2  = (const float*)d_in[1];
  const float* B2  = (const float*)d_in[2];
  const float* D   = (const float*)d_in[3];
  const float* Lam = (const float*)d_in[4];
  float* out = (float*)d_out;

  const size_t PL = (size_t)128 * NT;                 // dwords per pair plane
  const size_t need = PL * 4                          // Uph
                    + PL * 8                          // Yp float2
                    + 2 * 65536 * 2 + 2 * 131072 * 2; // Mb, Mc bf16 hi/lo

  if (ws_size >= need) {
    unsigned int* Uph = (unsigned int*)d_ws;
    float2* Yp = (float2*)(Uph + PL);
    unsigned short* Mbh = (unsigned short*)(Yp + PL);
    unsigned short* Mbl = Mbh + 65536;
    unsigned short* Mch = Mbl + 65536;
    unsigned short* Mcl = Mch + 131072;

    precomp_pack<<<dim3(128, 3), 128, 0, stream>>>(C2, B2, D, Mbh, Mbl, Mch, Mcl);
    fft_fwd_pack<<<NB * NH, 256, 0, stream>>>(u, Uph);
    gemm_fused<<<NT / 64, 256, 0, stream>>>(Mbh, Mbl, Mch, Mcl, Uph, Lam, Yp);
    fft_inv_gelu_pl<<<NB * NH, 256, 0, stream>>>(Yp, out);
  } else {
    float* ws = (float*)d_ws;
    const size_t nUc = (size_t)NB * NH * LF;
    cpx* U  = (cpx*)ws;
    cpx* Yf = U;
    float* Bt = ws + 2 * nUc;
    float* Ct = Bt + 32768;
    float* Dt = Ct + 32768;
    fb_precomp<<<dim3(128, 3), 128, 0, stream>>>(C2, B2, D, Bt, Ct, Dt);
    fb_fft_fwd<<<NB * NH, 256, 0, stream>>>(u, U);
    fb_mix<<<dim3(129, NB), 256, 0, stream>>>(U, Bt, Ct, Dt, Lam, Yf);
    fb_fft_inv<<<NB * NH, 256, 0, stream>>>(Yf, out);
  }
}